// Round 5
// baseline (4227.544 us; speedup 1.0000x reference)
//
#include <hip/hip_runtime.h>

// STATE=4096, CDIM=1024, fan_in=5121. RK4 x 4 steps = 16 aug-dynamics evals
// = 64 matvec phases. Persistent kernel (plain launch): both 4096x4096 weight
// matrices live in REGISTERS. Round-4 lesson: us8 w[16] allocas exceed
// AMDGPUPromoteAlloca's size cap -> scratch (VGPR=108, 1.25GB refetch). Fix:
// struct of 16 NAMED us8 fields, member-only access => SROA to SSA values,
// no alloca. __launch_bounds__(256,2) => 2 blocks/CU x 256 CU = 512 resident.
// Grid sync: per-block release flag + block-0 aggregate + 'go' broadcast,
// acquire spin-loads, agent scope (cross-XCD correct per G16).
#define N      4096
#define NC     1024
#define STEPS  4
#define TPB    256
#define NBLK   512

typedef unsigned short us8 __attribute__((ext_vector_type(8)));

struct WTile {
  us8 r0, r1, r2, r3, r4, r5, r6, r7, r8, r9, r10, r11, r12, r13, r14, r15;
};

__device__ __forceinline__ float bf2f(unsigned short u) {
  union { unsigned int i; float f; } v; v.i = ((unsigned int)u) << 16; return v.f;
}
__device__ __forceinline__ unsigned short f2bf(float f) {
  union { float f; unsigned int i; } v; v.f = f;
  const unsigned int u = v.i;
  return (unsigned short)((u + 0x7FFFu + ((u >> 16) & 1u)) >> 16);  // RNE
}
__device__ __forceinline__ float sigf(float x) { return 1.0f / (1.0f + __expf(-x)); }
__device__ __forceinline__ us8 cvt8(const float4 a, const float4 b) {
  us8 o;
  o[0] = f2bf(a.x); o[1] = f2bf(a.y); o[2] = f2bf(a.z); o[3] = f2bf(a.w);
  o[4] = f2bf(b.x); o[5] = f2bf(b.y); o[6] = f2bf(b.z); o[7] = f2bf(b.w);
  return o;
}

// ---------------------------------------------------------------------------
__global__ __launch_bounds__(TPB) void k_init(const float* __restrict__ h,
                                              const float* __restrict__ b1,
                                              const float* __restrict__ b2,
                                              float* __restrict__ ycur,
                                              float* __restrict__ cp1,
                                              float* __restrict__ cp2,
                                              float* __restrict__ rk,
                                              unsigned* __restrict__ flags) {
  const int j = blockIdx.x * TPB + threadIdx.x;
  if (j < N) { ycur[j] = h[j]; cp1[j] = b1[j]; cp2[j] = b2[j]; }
  if (j < 16) rk[j] = 0.f;
  if (j < 544) flags[j] = 0u;   // 512 arrive-flags + go + pad; re-zero per replay
}

// cp += c @ W[0:NC]  (fp32, once). grid (16, 8, 2), block 256.
__global__ __launch_bounds__(TPB) void k_cpart(const float* __restrict__ W1,
                                               const float* __restrict__ W2,
                                               const float* __restrict__ c,
                                               float* __restrict__ cp1,
                                               float* __restrict__ cp2) {
  const float* __restrict__ W = blockIdx.z ? W2 : W1;
  float* __restrict__ cp = blockIdx.z ? cp2 : cp1;
  __shared__ float xs[128];
  __shared__ float red[8][256];
  const int tid = threadIdx.x;
  const int cb = blockIdx.x, rc = blockIdx.y;
  const int r0 = rc * 128;
  if (tid < 128) xs[tid] = c[r0 + tid];
  __syncthreads();
  const int cg = tid & 31, rg = tid >> 5;
  const float* __restrict__ wbase = W + (size_t)r0 * N + cb * 256 + cg * 8;
  float a[8] = {0,0,0,0,0,0,0,0};
#pragma unroll
  for (int k = 0; k < 16; ++k) {
    const int r = rg + (k << 3);
    const float xv = xs[r];
    const float4 wa = *reinterpret_cast<const float4*>(wbase + (size_t)r * N);
    const float4 wb = *reinterpret_cast<const float4*>(wbase + (size_t)r * N + 4);
    a[0] = fmaf(wa.x, xv, a[0]); a[1] = fmaf(wa.y, xv, a[1]);
    a[2] = fmaf(wa.z, xv, a[2]); a[3] = fmaf(wa.w, xv, a[3]);
    a[4] = fmaf(wb.x, xv, a[4]); a[5] = fmaf(wb.y, xv, a[5]);
    a[6] = fmaf(wb.z, xv, a[6]); a[7] = fmaf(wb.w, xv, a[7]);
  }
#pragma unroll
  for (int e = 0; e < 8; ++e) red[rg][cg * 8 + e] = a[e];
  __syncthreads();
  float ssum = 0.f;
#pragma unroll
  for (int g = 0; g < 8; ++g) ssum += red[g][tid];
  atomicAdd(&cp[cb * 256 + tid], ssum);
}

// ---------------------------------------------------------------------------
// Grid barrier, monotonic rounds (identical to the verified round-4 barrier).
__device__ __forceinline__ void gsync(unsigned* flags, unsigned* go,
                                      const unsigned round,
                                      const int bid, const int tid) {
  __syncthreads();
  if (bid == 0) {
    if (tid == 0)
      __hip_atomic_store(&flags[0], round, __ATOMIC_RELEASE, __HIP_MEMORY_SCOPE_AGENT);
    while (__hip_atomic_load(&flags[tid], __ATOMIC_ACQUIRE, __HIP_MEMORY_SCOPE_AGENT) < round ||
           __hip_atomic_load(&flags[tid + 256], __ATOMIC_ACQUIRE, __HIP_MEMORY_SCOPE_AGENT) < round) {
      __builtin_amdgcn_s_sleep(1);
    }
    __syncthreads();
    if (tid == 0)
      __hip_atomic_store(go, round, __ATOMIC_RELEASE, __HIP_MEMORY_SCOPE_AGENT);
  } else {
    if (tid == 0) {
      __hip_atomic_store(&flags[bid], round, __ATOMIC_RELEASE, __HIP_MEMORY_SCOPE_AGENT);
      while (__hip_atomic_load(go, __ATOMIC_ACQUIRE, __HIP_MEMORY_SCOPE_AGENT) < round) {
        __builtin_amdgcn_s_sleep(1);
      }
    }
    __syncthreads();
  }
}

// ---------------------------------------------------------------------------
// One phase: reduce previous partials (2 halves x 16 over all 256 threads)
// -> epilogue (per mode, tid<128) -> build x chunk -> matvec from REGISTER
// weights (named struct fields, macro-unrolled) -> write partials.
// Modes: 0=FIRST(x=sig(h)), 1=P2(u1), 2=P3(f,tangent-L1 in), 3=P4(du1,RK),
//        4=PD(df,rk,next-stage x1).
// ---------------------------------------------------------------------------
__device__ __forceinline__ void phase_body(
    const int mode, const WTile& w, const us8 wrow, const bool doT,
    const float* __restrict__ pin, float* __restrict__ pout,
    const float* __restrict__ cpart,
    float* __restrict__ u1, float* __restrict__ fcur,
    const float* __restrict__ fprev,
    float* __restrict__ ycur, float* __restrict__ ksum,
    float* __restrict__ rk, const int rkIdx, const int s,
    const float csv, const float coef, const float dtv,
    float (&xs)[128], float (&red)[8][256],
    const int tid, const int cb, const int rc, const int j0,
    const int cg, const int rg) {
  // partial reduce split across all 256 threads (red[0..1][0..127] reused)
  if (mode != 0) {
    const int jl = tid & 127, half = tid >> 7;
    const float* __restrict__ pp = pin + ((half << 4) << 12) + j0 + jl;
    float ps = 0.f;
#pragma unroll
    for (int r = 0; r < 16; ++r) ps += pp[(size_t)(r << 12)];
    red[half][jl] = ps;
  }
  __syncthreads();

  if (tid < 128) {
    const int j = j0 + tid;
    float xv;
    if (mode == 0) {                       // FIRST: x1 = sig(h)
      xv = sigf(ycur[j]);
    } else {
      const float ssum = red[0][tid] + red[1][tid];
      if (mode == 1) {                     // P2: u1 = red + cpart1; x2 = sig(u1)
        const float u = ssum + cpart[j];
        if (cb == 0) u1[j] = u;
        xv = sigf(u);
      } else if (mode == 2) {              // P3: f = red + cpart2; v1 = s0'(ys)*f
        const float fv = ssum + cpart[j];
        if (cb == 0) fcur[j] = fv;
        float ys = ycur[j];
        if (csv != 0.f) ys = fmaf(csv * dtv, fprev[j], ys);
        const float s0 = sigf(ys);
        xv = s0 * (1.f - s0) * fv;
      } else if (mode == 3) {              // P4: du1 = red; v2 = s1'(u1)*du1; RK
        if (cb == 0) {
          const float fc = fcur[j];
          if (s == 0)      ksum[j] = fc;
          else if (s < 3)  ksum[j] = fmaf(2.f, fc, ksum[j]);
          else             ycur[j] = fmaf(dtv * (1.f / 6.f), ksum[j] + fc, ycur[j]);
        }
        const float s1 = sigf(u1[j]);
        xv = s1 * (1.f - s1) * ssum;
      } else {                             // PD: df = red; rk += df^2; x1 next
        float v = ssum * ssum;
#pragma unroll
        for (int off = 32; off >= 1; off >>= 1) v += __shfl_down(v, off);
        if (cb == 0 && (tid & 63) == 0) atomicAdd(&rk[rkIdx], v);
        float ys = ycur[j];
        if (csv != 0.f) ys = fmaf(csv * dtv, fprev[j], ys);
        xv = sigf(ys);
      }
    }
    xs[tid] = xv;
  }
  __syncthreads();

  float a[8] = {0,0,0,0,0,0,0,0};
#define MV_STEP(K, MEM)                                                        \
  {                                                                            \
    const float xv = xs[rg + (K << 3)];                                        \
    const us8 wk = w.MEM;                                                      \
    a[0] = fmaf(bf2f(wk[0]), xv, a[0]); a[1] = fmaf(bf2f(wk[1]), xv, a[1]);    \
    a[2] = fmaf(bf2f(wk[2]), xv, a[2]); a[3] = fmaf(bf2f(wk[3]), xv, a[3]);    \
    a[4] = fmaf(bf2f(wk[4]), xv, a[4]); a[5] = fmaf(bf2f(wk[5]), xv, a[5]);    \
    a[6] = fmaf(bf2f(wk[6]), xv, a[6]); a[7] = fmaf(bf2f(wk[7]), xv, a[7]);    \
  }
  MV_STEP(0, r0)  MV_STEP(1, r1)  MV_STEP(2, r2)   MV_STEP(3, r3)
  MV_STEP(4, r4)  MV_STEP(5, r5)  MV_STEP(6, r6)   MV_STEP(7, r7)
  MV_STEP(8, r8)  MV_STEP(9, r9)  MV_STEP(10, r10) MV_STEP(11, r11)
  MV_STEP(12, r12) MV_STEP(13, r13) MV_STEP(14, r14) MV_STEP(15, r15)
#undef MV_STEP
  if (doT) {                               // t-row contribution
#pragma unroll
    for (int e = 0; e < 8; ++e) a[e] = fmaf(bf2f(wrow[e]), coef, a[e]);
  }
#pragma unroll
  for (int e = 0; e < 8; ++e) red[rg][cg * 8 + e] = a[e];
  __syncthreads();
  float ssum = 0.f;
#pragma unroll
  for (int g = 0; g < 8; ++g) ssum += red[g][tid];
  pout[(rc << 12) + cb * 256 + tid] = ssum;
}

// ---------------------------------------------------------------------------
__global__ __launch_bounds__(TPB, 2) void k_ode(
    const float* __restrict__ W1f, const float* __restrict__ W2f,
    const float* __restrict__ tptr,
    float* __restrict__ partA, float* __restrict__ partB,
    const float* __restrict__ cp1, const float* __restrict__ cp2,
    float* __restrict__ u1, float* __restrict__ fb0, float* __restrict__ fb1,
    float* __restrict__ ycur, float* __restrict__ ksum,
    float* __restrict__ rk, unsigned* flags) {
  __shared__ float xs[128];
  __shared__ float red[8][256];
  const int tid = threadIdx.x;
  const int bid = blockIdx.x;
  const int cb = bid & 15, rc = bid >> 4;
  const int j0 = rc * 128;
  const int cg = tid & 31, rg = tid >> 5;
  unsigned* go = flags + 512;

  // ---- one-time: fp32 -> bf16 (RNE) weight tiles into NAMED registers ----
  const size_t colOff = (size_t)(cb * 256 + cg * 8);
  const float* __restrict__ w1p = W1f + (size_t)(NC + j0 + rg) * N + colOff;
  const float* __restrict__ w2p = W2f + (size_t)(NC + j0 + rg) * N + colOff;
  WTile w1, w2;
#define LDW(K, MEM)                                                            \
  {                                                                            \
    const size_t off = (size_t)(K << 3) * N;                                   \
    w1.MEM = cvt8(*reinterpret_cast<const float4*>(w1p + off),                 \
                  *reinterpret_cast<const float4*>(w1p + off + 4));            \
    w2.MEM = cvt8(*reinterpret_cast<const float4*>(w2p + off),                 \
                  *reinterpret_cast<const float4*>(w2p + off + 4));            \
  }
  LDW(0, r0)  LDW(1, r1)  LDW(2, r2)   LDW(3, r3)
  LDW(4, r4)  LDW(5, r5)  LDW(6, r6)   LDW(7, r7)
  LDW(8, r8)  LDW(9, r9)  LDW(10, r10) LDW(11, r11)
  LDW(12, r12) LDW(13, r13) LDW(14, r14) LDW(15, r15)
#undef LDW
  const bool doT = (rc == 31 && rg == 0);
  us8 wt1 = w1.r0, wt2 = w2.r0;
  if (doT) {
    const float* tp1 = W1f + (size_t)(NC + N) * N + colOff;
    const float* tp2 = W2f + (size_t)(NC + N) * N + colOff;
    wt1 = cvt8(*reinterpret_cast<const float4*>(tp1),
               *reinterpret_cast<const float4*>(tp1 + 4));
    wt2 = cvt8(*reinterpret_cast<const float4*>(tp2),
               *reinterpret_cast<const float4*>(tp2 + 4));
  }
  const float dtv = tptr[0] * (1.0f / STEPS);

  // ---- 16 evals x 4 phases, grid sync between phases ----
  float* pA = partA;
  float* pB = partB;
  unsigned sn = 0;

  for (int i = 0; i < 16; ++i) {
    const int s = i & 3;
    const float csv = (s == 0) ? 0.f : ((s == 3) ? 1.f : 0.5f);
    const float tcoef = ((float)(i >> 2) + csv) * dtv;
    float* fcur = (i & 1) ? fb1 : fb0;
    const float* fprev = (i & 1) ? fb0 : fb1;

    // P1: u1 partials = x1 @ W1_state (FIRST for i=0, PD otherwise)
    phase_body((i == 0) ? 0 : 4, w1, wt1, doT, pB, pA, cp1, u1, fcur, fprev,
               ycur, ksum, rk, i - 1, s, csv, tcoef, dtv, xs, red,
               tid, cb, rc, j0, cg, rg);
    { float* tp = pA; pA = pB; pB = tp; }
    ++sn; gsync(flags, go, sn, bid, tid);

    // P2: f partials = sig(u1+cp1) @ W2_state
    phase_body(1, w2, wt2, doT, pB, pA, cp1, u1, fcur, fprev, ycur, ksum, rk,
               0, s, csv, tcoef, dtv, xs, red, tid, cb, rc, j0, cg, rg);
    { float* tp = pA; pA = pB; pB = tp; }
    ++sn; gsync(flags, go, sn, bid, tid);

    // P3: du1 partials = (sig'(ys)*f) @ W1_state, t-coef 1
    phase_body(2, w1, wt1, doT, pB, pA, cp2, u1, fcur, fprev, ycur, ksum, rk,
               0, s, csv, 1.f, dtv, xs, red, tid, cb, rc, j0, cg, rg);
    { float* tp = pA; pA = pB; pB = tp; }
    ++sn; gsync(flags, go, sn, bid, tid);

    // P4: df partials = (sig'(u1)*du1) @ W2_state, t-coef 1; RK bookkeeping
    phase_body(3, w2, wt2, doT, pB, pA, cp2, u1, fcur, fprev, ycur, ksum, rk,
               0, s, csv, 1.f, dtv, xs, red, tid, cb, rc, j0, cg, rg);
    { float* tp = pA; pA = pB; pB = tp; }
    if (i < 15) { ++sn; gsync(flags, go, sn, bid, tid); }
  }
}

// Reduce the final P4 partials -> rk[15]; copy ycur -> out.
__global__ __launch_bounds__(128) void k_last(const float* __restrict__ part_in,
                                              const float* __restrict__ ycur,
                                              float* __restrict__ rk,
                                              float* __restrict__ out) {
  const int tid = threadIdx.x;
  const int j = blockIdx.x * 128 + tid;
  float df = 0.f;
#pragma unroll 8
  for (int r = 0; r < 32; ++r) df += part_in[(r << 12) + j];
  float v = df * df;
#pragma unroll
  for (int off = 32; off >= 1; off >>= 1) v += __shfl_down(v, off);
  if ((tid & 63) == 0) atomicAdd(&rk[15], v);
  out[j] = ycur[j];
}

__global__ void k_out(const float* __restrict__ rk, const float* __restrict__ tptr,
                      float* __restrict__ out) {
  if (threadIdx.x == 0) {
    const float dtv = tptr[0] * (1.0f / STEPS);
    float r = 0.f;
    for (int st = 0; st < STEPS; ++st)
      r += rk[4 * st] + 2.f * rk[4 * st + 1] + 2.f * rk[4 * st + 2] + rk[4 * st + 3];
    out[N] = r * (dtv / 6.f) * (1.0f / N);
  }
}

// ---------------------------------------------------------------------------
extern "C" void kernel_launch(void* const* d_in, const int* in_sizes, int n_in,
                              void* d_out, int out_size, void* d_ws, size_t ws_size,
                              hipStream_t stream) {
  const float* h  = (const float*)d_in[0];
  const float* t  = (const float*)d_in[1];
  const float* c  = (const float*)d_in[2];
  const float* W1 = (const float*)d_in[3];
  const float* b1 = (const float*)d_in[4];
  const float* W2 = (const float*)d_in[5];
  const float* b2 = (const float*)d_in[6];
  float* out = (float*)d_out;

  // ws: fp32 buffers + flags (~1.2 MB) — weights live in registers.
  float* fp    = (float*)d_ws;
  float* partA = fp;                     // 32*4096
  float* partB = partA + 32 * N;
  float* cp1   = partB + 32 * N;
  float* cp2   = cp1 + N;
  float* u1    = cp2 + N;
  float* fb0   = u1 + N;
  float* fb1   = fb0 + N;
  float* ycur  = fb1 + N;
  float* ksum  = ycur + N;
  float* rk    = ksum + N;               // 16
  unsigned* flags = (unsigned*)(rk + 16); // 512 flags + go + pad

  k_init<<<16, TPB, 0, stream>>>(h, b1, b2, ycur, cp1, cp2, rk, flags);
  k_cpart<<<dim3(16, 8, 2), TPB, 0, stream>>>(W1, W2, c, cp1, cp2);

  k_ode<<<NBLK, TPB, 0, stream>>>(W1, W2, t, partA, partB, cp1, cp2,
                                  u1, fb0, fb1, ycur, ksum, rk, flags);

  k_last<<<32, 128, 0, stream>>>(partB, ycur, rk, out);
  k_out<<<1, 64, 0, stream>>>(rk, t, out);
}

// Round 6
// 4168.295 us; speedup vs baseline: 1.0142x; 1.0142x over previous
//
#include <hip/hip_runtime.h>

// STATE=4096, CDIM=1024, fan_in=5121. RK4 x 4 steps = 16 aug-dynamics evals
// = 64 matvec phases. Persistent kernel (plain launch): both 4096x4096 weight
// matrices live in REGISTERS (128 VGPR: 512 blocks x 256 thr x 256B).
// Round-4 lesson: us8 w[16] alloca -> scratch. Round-5 lesson: SROA alone
// insufficient — allocator spills loop-invariant loads to chase occupancy
// (VGPR=128 = 4 waves/SIMD). Fix: amdgpu_waves_per_eu(2,2) pins max occupancy
// to 2 waves/EU so there is no occupancy reward for spilling; allocator may
// use up to 256 VGPR. 2 blocks/CU x 256 CU = 512 resident (barrier proven
// sound at this occupancy in rounds 4-5). Grid sync: per-block release flag
// + block-0 aggregate + 'go' broadcast, acquire spin-loads, agent scope.
#define N      4096
#define NC     1024
#define STEPS  4
#define TPB    256
#define NBLK   512

typedef unsigned short us8 __attribute__((ext_vector_type(8)));

struct WTile {
  us8 r0, r1, r2, r3, r4, r5, r6, r7, r8, r9, r10, r11, r12, r13, r14, r15;
};

__device__ __forceinline__ float bf2f(unsigned short u) {
  union { unsigned int i; float f; } v; v.i = ((unsigned int)u) << 16; return v.f;
}
__device__ __forceinline__ unsigned short f2bf(float f) {
  union { float f; unsigned int i; } v; v.f = f;
  const unsigned int u = v.i;
  return (unsigned short)((u + 0x7FFFu + ((u >> 16) & 1u)) >> 16);  // RNE
}
__device__ __forceinline__ float sigf(float x) { return 1.0f / (1.0f + __expf(-x)); }
__device__ __forceinline__ us8 cvt8(const float4 a, const float4 b) {
  us8 o;
  o[0] = f2bf(a.x); o[1] = f2bf(a.y); o[2] = f2bf(a.z); o[3] = f2bf(a.w);
  o[4] = f2bf(b.x); o[5] = f2bf(b.y); o[6] = f2bf(b.z); o[7] = f2bf(b.w);
  return o;
}

// ---------------------------------------------------------------------------
__global__ __launch_bounds__(TPB) void k_init(const float* __restrict__ h,
                                              const float* __restrict__ b1,
                                              const float* __restrict__ b2,
                                              float* __restrict__ ycur,
                                              float* __restrict__ cp1,
                                              float* __restrict__ cp2,
                                              float* __restrict__ rk,
                                              unsigned* __restrict__ flags) {
  const int j = blockIdx.x * TPB + threadIdx.x;
  if (j < N) { ycur[j] = h[j]; cp1[j] = b1[j]; cp2[j] = b2[j]; }
  if (j < 16) rk[j] = 0.f;
  if (j < 544) flags[j] = 0u;   // 512 arrive-flags + go + pad; re-zero per replay
}

// cp += c @ W[0:NC]  (fp32, once). grid (16, 8, 2), block 256.
__global__ __launch_bounds__(TPB) void k_cpart(const float* __restrict__ W1,
                                               const float* __restrict__ W2,
                                               const float* __restrict__ c,
                                               float* __restrict__ cp1,
                                               float* __restrict__ cp2) {
  const float* __restrict__ W = blockIdx.z ? W2 : W1;
  float* __restrict__ cp = blockIdx.z ? cp2 : cp1;
  __shared__ float xs[128];
  __shared__ float red[8][256];
  const int tid = threadIdx.x;
  const int cb = blockIdx.x, rc = blockIdx.y;
  const int r0 = rc * 128;
  if (tid < 128) xs[tid] = c[r0 + tid];
  __syncthreads();
  const int cg = tid & 31, rg = tid >> 5;
  const float* __restrict__ wbase = W + (size_t)r0 * N + cb * 256 + cg * 8;
  float a[8] = {0,0,0,0,0,0,0,0};
#pragma unroll
  for (int k = 0; k < 16; ++k) {
    const int r = rg + (k << 3);
    const float xv = xs[r];
    const float4 wa = *reinterpret_cast<const float4*>(wbase + (size_t)r * N);
    const float4 wb = *reinterpret_cast<const float4*>(wbase + (size_t)r * N + 4);
    a[0] = fmaf(wa.x, xv, a[0]); a[1] = fmaf(wa.y, xv, a[1]);
    a[2] = fmaf(wa.z, xv, a[2]); a[3] = fmaf(wa.w, xv, a[3]);
    a[4] = fmaf(wb.x, xv, a[4]); a[5] = fmaf(wb.y, xv, a[5]);
    a[6] = fmaf(wb.z, xv, a[6]); a[7] = fmaf(wb.w, xv, a[7]);
  }
#pragma unroll
  for (int e = 0; e < 8; ++e) red[rg][cg * 8 + e] = a[e];
  __syncthreads();
  float ssum = 0.f;
#pragma unroll
  for (int g = 0; g < 8; ++g) ssum += red[g][tid];
  atomicAdd(&cp[cb * 256 + tid], ssum);
}

// ---------------------------------------------------------------------------
// Grid barrier, monotonic rounds (identical to the verified round-4 barrier).
__device__ __forceinline__ void gsync(unsigned* flags, unsigned* go,
                                      const unsigned round,
                                      const int bid, const int tid) {
  __syncthreads();
  if (bid == 0) {
    if (tid == 0)
      __hip_atomic_store(&flags[0], round, __ATOMIC_RELEASE, __HIP_MEMORY_SCOPE_AGENT);
    while (__hip_atomic_load(&flags[tid], __ATOMIC_ACQUIRE, __HIP_MEMORY_SCOPE_AGENT) < round ||
           __hip_atomic_load(&flags[tid + 256], __ATOMIC_ACQUIRE, __HIP_MEMORY_SCOPE_AGENT) < round) {
      __builtin_amdgcn_s_sleep(1);
    }
    __syncthreads();
    if (tid == 0)
      __hip_atomic_store(go, round, __ATOMIC_RELEASE, __HIP_MEMORY_SCOPE_AGENT);
  } else {
    if (tid == 0) {
      __hip_atomic_store(&flags[bid], round, __ATOMIC_RELEASE, __HIP_MEMORY_SCOPE_AGENT);
      while (__hip_atomic_load(go, __ATOMIC_ACQUIRE, __HIP_MEMORY_SCOPE_AGENT) < round) {
        __builtin_amdgcn_s_sleep(1);
      }
    }
    __syncthreads();
  }
}

// ---------------------------------------------------------------------------
// One phase: reduce previous partials (2 halves x 16 over all 256 threads)
// -> epilogue (per mode, tid<128) -> build x chunk -> matvec from REGISTER
// weights (named struct fields, macro-unrolled) -> write partials.
// Modes: 0=FIRST(x=sig(h)), 1=P2(u1), 2=P3(f,tangent-L1 in), 3=P4(du1,RK),
//        4=PD(df,rk,next-stage x1).
// ---------------------------------------------------------------------------
__device__ __forceinline__ void phase_body(
    const int mode, const WTile& w, const us8 wrow, const bool doT,
    const float* __restrict__ pin, float* __restrict__ pout,
    const float* __restrict__ cpart,
    float* __restrict__ u1, float* __restrict__ fcur,
    const float* __restrict__ fprev,
    float* __restrict__ ycur, float* __restrict__ ksum,
    float* __restrict__ rk, const int rkIdx, const int s,
    const float csv, const float coef, const float dtv,
    float (&xs)[128], float (&red)[8][256],
    const int tid, const int cb, const int rc, const int j0,
    const int cg, const int rg) {
  // partial reduce split across all 256 threads (red[0..1][0..127] reused)
  if (mode != 0) {
    const int jl = tid & 127, half = tid >> 7;
    const float* __restrict__ pp = pin + ((half << 4) << 12) + j0 + jl;
    float ps = 0.f;
#pragma unroll
    for (int r = 0; r < 16; ++r) ps += pp[(size_t)(r << 12)];
    red[half][jl] = ps;
  }
  __syncthreads();

  if (tid < 128) {
    const int j = j0 + tid;
    float xv;
    if (mode == 0) {                       // FIRST: x1 = sig(h)
      xv = sigf(ycur[j]);
    } else {
      const float ssum = red[0][tid] + red[1][tid];
      if (mode == 1) {                     // P2: u1 = red + cpart1; x2 = sig(u1)
        const float u = ssum + cpart[j];
        if (cb == 0) u1[j] = u;
        xv = sigf(u);
      } else if (mode == 2) {              // P3: f = red + cpart2; v1 = s0'(ys)*f
        const float fv = ssum + cpart[j];
        if (cb == 0) fcur[j] = fv;
        float ys = ycur[j];
        if (csv != 0.f) ys = fmaf(csv * dtv, fprev[j], ys);
        const float s0 = sigf(ys);
        xv = s0 * (1.f - s0) * fv;
      } else if (mode == 3) {              // P4: du1 = red; v2 = s1'(u1)*du1; RK
        if (cb == 0) {
          const float fc = fcur[j];
          if (s == 0)      ksum[j] = fc;
          else if (s < 3)  ksum[j] = fmaf(2.f, fc, ksum[j]);
          else             ycur[j] = fmaf(dtv * (1.f / 6.f), ksum[j] + fc, ycur[j]);
        }
        const float s1 = sigf(u1[j]);
        xv = s1 * (1.f - s1) * ssum;
      } else {                             // PD: df = red; rk += df^2; x1 next
        float v = ssum * ssum;
#pragma unroll
        for (int off = 32; off >= 1; off >>= 1) v += __shfl_down(v, off);
        if (cb == 0 && (tid & 63) == 0) atomicAdd(&rk[rkIdx], v);
        float ys = ycur[j];
        if (csv != 0.f) ys = fmaf(csv * dtv, fprev[j], ys);
        xv = sigf(ys);
      }
    }
    xs[tid] = xv;
  }
  __syncthreads();

  float a[8] = {0,0,0,0,0,0,0,0};
#define MV_STEP(K, MEM)                                                        \
  {                                                                            \
    const float xv = xs[rg + (K << 3)];                                        \
    const us8 wk = w.MEM;                                                      \
    a[0] = fmaf(bf2f(wk[0]), xv, a[0]); a[1] = fmaf(bf2f(wk[1]), xv, a[1]);    \
    a[2] = fmaf(bf2f(wk[2]), xv, a[2]); a[3] = fmaf(bf2f(wk[3]), xv, a[3]);    \
    a[4] = fmaf(bf2f(wk[4]), xv, a[4]); a[5] = fmaf(bf2f(wk[5]), xv, a[5]);    \
    a[6] = fmaf(bf2f(wk[6]), xv, a[6]); a[7] = fmaf(bf2f(wk[7]), xv, a[7]);    \
  }
  MV_STEP(0, r0)  MV_STEP(1, r1)  MV_STEP(2, r2)   MV_STEP(3, r3)
  MV_STEP(4, r4)  MV_STEP(5, r5)  MV_STEP(6, r6)   MV_STEP(7, r7)
  MV_STEP(8, r8)  MV_STEP(9, r9)  MV_STEP(10, r10) MV_STEP(11, r11)
  MV_STEP(12, r12) MV_STEP(13, r13) MV_STEP(14, r14) MV_STEP(15, r15)
#undef MV_STEP
  if (doT) {                               // t-row contribution
#pragma unroll
    for (int e = 0; e < 8; ++e) a[e] = fmaf(bf2f(wrow[e]), coef, a[e]);
  }
#pragma unroll
  for (int e = 0; e < 8; ++e) red[rg][cg * 8 + e] = a[e];
  __syncthreads();
  float ssum = 0.f;
#pragma unroll
  for (int g = 0; g < 8; ++g) ssum += red[g][tid];
  pout[(rc << 12) + cb * 256 + tid] = ssum;
}

// ---------------------------------------------------------------------------
// waves_per_eu(2,2): min AND max 2 waves/EU. Max=2 removes any occupancy
// reward for spilling, so the allocator keeps the 128 weight VGPRs resident
// (round-5 failure mode: min-only bound -> allocator capped at 128 VGPR /
// 4 waves and spilled the loop-invariant weight loads to scratch).
__global__ __launch_bounds__(TPB)
__attribute__((amdgpu_waves_per_eu(2, 2)))
void k_ode(
    const float* __restrict__ W1f, const float* __restrict__ W2f,
    const float* __restrict__ tptr,
    float* __restrict__ partA, float* __restrict__ partB,
    const float* __restrict__ cp1, const float* __restrict__ cp2,
    float* __restrict__ u1, float* __restrict__ fb0, float* __restrict__ fb1,
    float* __restrict__ ycur, float* __restrict__ ksum,
    float* __restrict__ rk, unsigned* flags) {
  __shared__ float xs[128];
  __shared__ float red[8][256];
  const int tid = threadIdx.x;
  const int bid = blockIdx.x;
  const int cb = bid & 15, rc = bid >> 4;
  const int j0 = rc * 128;
  const int cg = tid & 31, rg = tid >> 5;
  unsigned* go = flags + 512;

  // ---- one-time: fp32 -> bf16 (RNE) weight tiles into NAMED registers ----
  const size_t colOff = (size_t)(cb * 256 + cg * 8);
  const float* __restrict__ w1p = W1f + (size_t)(NC + j0 + rg) * N + colOff;
  const float* __restrict__ w2p = W2f + (size_t)(NC + j0 + rg) * N + colOff;
  WTile w1, w2;
#define LDW(K, MEM)                                                            \
  {                                                                            \
    const size_t off = (size_t)(K << 3) * N;                                   \
    w1.MEM = cvt8(*reinterpret_cast<const float4*>(w1p + off),                 \
                  *reinterpret_cast<const float4*>(w1p + off + 4));            \
    w2.MEM = cvt8(*reinterpret_cast<const float4*>(w2p + off),                 \
                  *reinterpret_cast<const float4*>(w2p + off + 4));            \
  }
  LDW(0, r0)  LDW(1, r1)  LDW(2, r2)   LDW(3, r3)
  LDW(4, r4)  LDW(5, r5)  LDW(6, r6)   LDW(7, r7)
  LDW(8, r8)  LDW(9, r9)  LDW(10, r10) LDW(11, r11)
  LDW(12, r12) LDW(13, r13) LDW(14, r14) LDW(15, r15)
#undef LDW
  const bool doT = (rc == 31 && rg == 0);
  us8 wt1 = w1.r0, wt2 = w2.r0;
  if (doT) {
    const float* tp1 = W1f + (size_t)(NC + N) * N + colOff;
    const float* tp2 = W2f + (size_t)(NC + N) * N + colOff;
    wt1 = cvt8(*reinterpret_cast<const float4*>(tp1),
               *reinterpret_cast<const float4*>(tp1 + 4));
    wt2 = cvt8(*reinterpret_cast<const float4*>(tp2),
               *reinterpret_cast<const float4*>(tp2 + 4));
  }
  const float dtv = tptr[0] * (1.0f / STEPS);

  // ---- 16 evals x 4 phases, grid sync between phases ----
  float* pA = partA;
  float* pB = partB;
  unsigned sn = 0;

  for (int i = 0; i < 16; ++i) {
    const int s = i & 3;
    const float csv = (s == 0) ? 0.f : ((s == 3) ? 1.f : 0.5f);
    const float tcoef = ((float)(i >> 2) + csv) * dtv;
    float* fcur = (i & 1) ? fb1 : fb0;
    const float* fprev = (i & 1) ? fb0 : fb1;

    // P1: u1 partials = x1 @ W1_state (FIRST for i=0, PD otherwise)
    phase_body((i == 0) ? 0 : 4, w1, wt1, doT, pB, pA, cp1, u1, fcur, fprev,
               ycur, ksum, rk, i - 1, s, csv, tcoef, dtv, xs, red,
               tid, cb, rc, j0, cg, rg);
    { float* tp = pA; pA = pB; pB = tp; }
    ++sn; gsync(flags, go, sn, bid, tid);

    // P2: f partials = sig(u1+cp1) @ W2_state
    phase_body(1, w2, wt2, doT, pB, pA, cp1, u1, fcur, fprev, ycur, ksum, rk,
               0, s, csv, tcoef, dtv, xs, red, tid, cb, rc, j0, cg, rg);
    { float* tp = pA; pA = pB; pB = tp; }
    ++sn; gsync(flags, go, sn, bid, tid);

    // P3: du1 partials = (sig'(ys)*f) @ W1_state, t-coef 1
    phase_body(2, w1, wt1, doT, pB, pA, cp2, u1, fcur, fprev, ycur, ksum, rk,
               0, s, csv, 1.f, dtv, xs, red, tid, cb, rc, j0, cg, rg);
    { float* tp = pA; pA = pB; pB = tp; }
    ++sn; gsync(flags, go, sn, bid, tid);

    // P4: df partials = (sig'(u1)*du1) @ W2_state, t-coef 1; RK bookkeeping
    phase_body(3, w2, wt2, doT, pB, pA, cp2, u1, fcur, fprev, ycur, ksum, rk,
               0, s, csv, 1.f, dtv, xs, red, tid, cb, rc, j0, cg, rg);
    { float* tp = pA; pA = pB; pB = tp; }
    if (i < 15) { ++sn; gsync(flags, go, sn, bid, tid); }
  }
}

// Reduce the final P4 partials -> rk[15]; copy ycur -> out.
__global__ __launch_bounds__(128) void k_last(const float* __restrict__ part_in,
                                              const float* __restrict__ ycur,
                                              float* __restrict__ rk,
                                              float* __restrict__ out) {
  const int tid = threadIdx.x;
  const int j = blockIdx.x * 128 + tid;
  float df = 0.f;
#pragma unroll 8
  for (int r = 0; r < 32; ++r) df += part_in[(r << 12) + j];
  float v = df * df;
#pragma unroll
  for (int off = 32; off >= 1; off >>= 1) v += __shfl_down(v, off);
  if ((tid & 63) == 0) atomicAdd(&rk[15], v);
  out[j] = ycur[j];
}

__global__ void k_out(const float* __restrict__ rk, const float* __restrict__ tptr,
                      float* __restrict__ out) {
  if (threadIdx.x == 0) {
    const float dtv = tptr[0] * (1.0f / STEPS);
    float r = 0.f;
    for (int st = 0; st < STEPS; ++st)
      r += rk[4 * st] + 2.f * rk[4 * st + 1] + 2.f * rk[4 * st + 2] + rk[4 * st + 3];
    out[N] = r * (dtv / 6.f) * (1.0f / N);
  }
}

// ---------------------------------------------------------------------------
extern "C" void kernel_launch(void* const* d_in, const int* in_sizes, int n_in,
                              void* d_out, int out_size, void* d_ws, size_t ws_size,
                              hipStream_t stream) {
  const float* h  = (const float*)d_in[0];
  const float* t  = (const float*)d_in[1];
  const float* c  = (const float*)d_in[2];
  const float* W1 = (const float*)d_in[3];
  const float* b1 = (const float*)d_in[4];
  const float* W2 = (const float*)d_in[5];
  const float* b2 = (const float*)d_in[6];
  float* out = (float*)d_out;

  // ws: fp32 buffers + flags (~1.2 MB) — weights live in registers.
  float* fp    = (float*)d_ws;
  float* partA = fp;                     // 32*4096
  float* partB = partA + 32 * N;
  float* cp1   = partB + 32 * N;
  float* cp2   = cp1 + N;
  float* u1    = cp2 + N;
  float* fb0   = u1 + N;
  float* fb1   = fb0 + N;
  float* ycur  = fb1 + N;
  float* ksum  = ycur + N;
  float* rk    = ksum + N;               // 16
  unsigned* flags = (unsigned*)(rk + 16); // 512 flags + go + pad

  k_init<<<16, TPB, 0, stream>>>(h, b1, b2, ycur, cp1, cp2, rk, flags);
  k_cpart<<<dim3(16, 8, 2), TPB, 0, stream>>>(W1, W2, c, cp1, cp2);

  k_ode<<<NBLK, TPB, 0, stream>>>(W1, W2, t, partA, partB, cp1, cp2,
                                  u1, fb0, fb1, ycur, ksum, rk, flags);

  k_last<<<32, 128, 0, stream>>>(partB, ycur, rk, out);
  k_out<<<1, 64, 0, stream>>>(rk, t, out);
}

// Round 7
// 3897.974 us; speedup vs baseline: 1.0845x; 1.0693x over previous
//
#include <hip/hip_runtime.h>

// STATE=4096, CDIM=1024, fan_in=5121. RK4 x 4 steps = 16 aug-dynamics evals
// = 64 matvec phases. Persistent kernel: both 4096x4096 weight matrices live
// in AGPRs, pinned by inline asm (v_accvgpr_write/read). History: r4 array
// alloca -> scratch; r5 struct SROA -> allocator spills for occupancy; r6
// waves_per_eu(2,2) -> allocator STILL spills (VGPR=128, FETCH 1.27GB).
// Volatile-asm AGPR defs are non-rematerializable and non-sinkable, and the
// AGPR aperture (256 regs) is separate from the arch-VGPR budget the
// heuristic fights over. 136 AGPR/thread used. 2 blocks/CU x 256 CU = 512
// resident (barrier proven sound rounds 4-6). Grid sync: per-block release
// flag + block-0 aggregate + 'go' broadcast, acquire spin-loads, agent scope.
#define N      4096
#define NC     1024
#define STEPS  4
#define TPB    256
#define NBLK   512

typedef unsigned short us8 __attribute__((ext_vector_type(8)));

__device__ __forceinline__ float bf2f(unsigned short u) {
  union { unsigned int i; float f; } v; v.i = ((unsigned int)u) << 16; return v.f;
}
__device__ __forceinline__ unsigned short f2bf(float f) {
  union { float f; unsigned int i; } v; v.f = f;
  const unsigned int u = v.i;
  return (unsigned short)((u + 0x7FFFu + ((u >> 16) & 1u)) >> 16);  // RNE
}
__device__ __forceinline__ float sigf(float x) { return 1.0f / (1.0f + __expf(-x)); }
__device__ __forceinline__ us8 cvt8(const float4 a, const float4 b) {
  us8 o;
  o[0] = f2bf(a.x); o[1] = f2bf(a.y); o[2] = f2bf(a.z); o[3] = f2bf(a.w);
  o[4] = f2bf(b.x); o[5] = f2bf(b.y); o[6] = f2bf(b.z); o[7] = f2bf(b.w);
  return o;
}
// bf16 pair extraction from a packed dword — bit-identical to bf2f of each u16
__device__ __forceinline__ float lof(unsigned d) {
  union { unsigned u; float f; } v; v.u = d << 16; return v.f;
}
__device__ __forceinline__ float hif(unsigned d) {
  union { unsigned u; float f; } v; v.u = d & 0xffff0000u; return v.f;
}

// AGPR pin/read. Volatile: not sinkable/hoistable/CSE-able/remat-able.
#define AW(dst, src) \
  asm volatile("v_accvgpr_write_b32 %0, %1" : "=a"(dst) : "v"(src))
#define AR(dst, src) \
  asm volatile("v_accvgpr_read_b32 %0, %1" : "=v"(dst) : "a"(src))

// ---------------------------------------------------------------------------
__global__ __launch_bounds__(TPB) void k_init(const float* __restrict__ h,
                                              const float* __restrict__ b1,
                                              const float* __restrict__ b2,
                                              float* __restrict__ ycur,
                                              float* __restrict__ cp1,
                                              float* __restrict__ cp2,
                                              float* __restrict__ rk,
                                              unsigned* __restrict__ flags) {
  const int j = blockIdx.x * TPB + threadIdx.x;
  if (j < N) { ycur[j] = h[j]; cp1[j] = b1[j]; cp2[j] = b2[j]; }
  if (j < 16) rk[j] = 0.f;
  if (j < 544) flags[j] = 0u;   // 512 arrive-flags + go + pad; re-zero per replay
}

// cp += c @ W[0:NC]  (fp32, once). grid (16, 8, 2), block 256.
__global__ __launch_bounds__(TPB) void k_cpart(const float* __restrict__ W1,
                                               const float* __restrict__ W2,
                                               const float* __restrict__ c,
                                               float* __restrict__ cp1,
                                               float* __restrict__ cp2) {
  const float* __restrict__ W = blockIdx.z ? W2 : W1;
  float* __restrict__ cp = blockIdx.z ? cp2 : cp1;
  __shared__ float xs[128];
  __shared__ float red[8][256];
  const int tid = threadIdx.x;
  const int cb = blockIdx.x, rc = blockIdx.y;
  const int r0 = rc * 128;
  if (tid < 128) xs[tid] = c[r0 + tid];
  __syncthreads();
  const int cg = tid & 31, rg = tid >> 5;
  const float* __restrict__ wbase = W + (size_t)r0 * N + cb * 256 + cg * 8;
  float a[8] = {0,0,0,0,0,0,0,0};
#pragma unroll
  for (int k = 0; k < 16; ++k) {
    const int r = rg + (k << 3);
    const float xv = xs[r];
    const float4 wa = *reinterpret_cast<const float4*>(wbase + (size_t)r * N);
    const float4 wb = *reinterpret_cast<const float4*>(wbase + (size_t)r * N + 4);
    a[0] = fmaf(wa.x, xv, a[0]); a[1] = fmaf(wa.y, xv, a[1]);
    a[2] = fmaf(wa.z, xv, a[2]); a[3] = fmaf(wa.w, xv, a[3]);
    a[4] = fmaf(wb.x, xv, a[4]); a[5] = fmaf(wb.y, xv, a[5]);
    a[6] = fmaf(wb.z, xv, a[6]); a[7] = fmaf(wb.w, xv, a[7]);
  }
#pragma unroll
  for (int e = 0; e < 8; ++e) red[rg][cg * 8 + e] = a[e];
  __syncthreads();
  float ssum = 0.f;
#pragma unroll
  for (int g = 0; g < 8; ++g) ssum += red[g][tid];
  atomicAdd(&cp[cb * 256 + tid], ssum);
}

// ---------------------------------------------------------------------------
// Grid barrier, monotonic rounds (identical to the verified round-4 barrier).
__device__ __forceinline__ void gsync(unsigned* flags, unsigned* go,
                                      const unsigned round,
                                      const int bid, const int tid) {
  __syncthreads();
  if (bid == 0) {
    if (tid == 0)
      __hip_atomic_store(&flags[0], round, __ATOMIC_RELEASE, __HIP_MEMORY_SCOPE_AGENT);
    while (__hip_atomic_load(&flags[tid], __ATOMIC_ACQUIRE, __HIP_MEMORY_SCOPE_AGENT) < round ||
           __hip_atomic_load(&flags[tid + 256], __ATOMIC_ACQUIRE, __HIP_MEMORY_SCOPE_AGENT) < round) {
      __builtin_amdgcn_s_sleep(1);
    }
    __syncthreads();
    if (tid == 0)
      __hip_atomic_store(go, round, __ATOMIC_RELEASE, __HIP_MEMORY_SCOPE_AGENT);
  } else {
    if (tid == 0) {
      __hip_atomic_store(&flags[bid], round, __ATOMIC_RELEASE, __HIP_MEMORY_SCOPE_AGENT);
      while (__hip_atomic_load(go, __ATOMIC_ACQUIRE, __HIP_MEMORY_SCOPE_AGENT) < round) {
        __builtin_amdgcn_s_sleep(1);
      }
    }
    __syncthreads();
  }
}

// ---------------------------------------------------------------------------
// Epilogue of previous phase + build x chunk (everything except the matvec).
// Modes: 0=FIRST(x=sig(h)), 1=P2(u1), 2=P3(f,tangent-L1 in), 3=P4(du1,RK),
//        4=PD(df,rk,next-stage x1).
// ---------------------------------------------------------------------------
__device__ __forceinline__ void build_x(
    const int mode,
    const float* __restrict__ pin, const float* __restrict__ cpart,
    float* __restrict__ u1, float* __restrict__ fcur,
    const float* __restrict__ fprev,
    float* __restrict__ ycur, float* __restrict__ ksum,
    float* __restrict__ rk, const int rkIdx, const int s,
    const float csv, const float dtv,
    float (&xs)[128], float (&red)[8][256],
    const int tid, const int cb, const int rc, const int j0) {
  // partial reduce split across all 256 threads (red[0..1][0..127] reused)
  if (mode != 0) {
    const int jl = tid & 127, half = tid >> 7;
    const float* __restrict__ pp = pin + ((half << 4) << 12) + j0 + jl;
    float ps = 0.f;
#pragma unroll
    for (int r = 0; r < 16; ++r) ps += pp[(size_t)(r << 12)];
    red[half][jl] = ps;
  }
  __syncthreads();

  if (tid < 128) {
    const int j = j0 + tid;
    float xv;
    if (mode == 0) {                       // FIRST: x1 = sig(h)
      xv = sigf(ycur[j]);
    } else {
      const float ssum = red[0][tid] + red[1][tid];
      if (mode == 1) {                     // P2: u1 = red + cpart1; x2 = sig(u1)
        const float u = ssum + cpart[j];
        if (cb == 0) u1[j] = u;
        xv = sigf(u);
      } else if (mode == 2) {              // P3: f = red + cpart2; v1 = s0'(ys)*f
        const float fv = ssum + cpart[j];
        if (cb == 0) fcur[j] = fv;
        float ys = ycur[j];
        if (csv != 0.f) ys = fmaf(csv * dtv, fprev[j], ys);
        const float s0 = sigf(ys);
        xv = s0 * (1.f - s0) * fv;
      } else if (mode == 3) {              // P4: du1 = red; v2 = s1'(u1)*du1; RK
        if (cb == 0) {
          const float fc = fcur[j];
          if (s == 0)      ksum[j] = fc;
          else if (s < 3)  ksum[j] = fmaf(2.f, fc, ksum[j]);
          else             ycur[j] = fmaf(dtv * (1.f / 6.f), ksum[j] + fc, ycur[j]);
        }
        const float s1 = sigf(u1[j]);
        xv = s1 * (1.f - s1) * ssum;
      } else {                             // PD: df = red; rk += df^2; x1 next
        float v = ssum * ssum;
#pragma unroll
        for (int off = 32; off >= 1; off >>= 1) v += __shfl_down(v, off);
        if (cb == 0 && (tid & 63) == 0) atomicAdd(&rk[rkIdx], v);
        float ys = ycur[j];
        if (csv != 0.f) ys = fmaf(csv * dtv, fprev[j], ys);
        xv = sigf(ys);
      }
    }
    xs[tid] = xv;
  }
  __syncthreads();
}

// ---------------------------------------------------------------------------
// AGPR weight storage: 4 dwords per 16-row step, 16 steps per matrix.
#define DECL4(P) unsigned P##_0, P##_1, P##_2, P##_3;

#define LDW(M, K, SRCP)                                                        \
  {                                                                            \
    const size_t off = (size_t)(K << 3) * N;                                   \
    const uint4 q = __builtin_bit_cast(                                        \
        uint4, cvt8(*reinterpret_cast<const float4*>((SRCP) + off),            \
                    *reinterpret_cast<const float4*>((SRCP) + off + 4)));      \
    AW(M##_##K##_0, q.x); AW(M##_##K##_1, q.y);                                \
    AW(M##_##K##_2, q.z); AW(M##_##K##_3, q.w);                                \
  }

#define MV_STEP(M, K)                                                          \
  {                                                                            \
    const float xv = xs[rg + (K << 3)];                                        \
    unsigned d0, d1, d2, d3;                                                   \
    AR(d0, M##_##K##_0); AR(d1, M##_##K##_1);                                  \
    AR(d2, M##_##K##_2); AR(d3, M##_##K##_3);                                  \
    acc[0] = fmaf(lof(d0), xv, acc[0]); acc[1] = fmaf(hif(d0), xv, acc[1]);    \
    acc[2] = fmaf(lof(d1), xv, acc[2]); acc[3] = fmaf(hif(d1), xv, acc[3]);    \
    acc[4] = fmaf(lof(d2), xv, acc[4]); acc[5] = fmaf(hif(d2), xv, acc[5]);    \
    acc[6] = fmaf(lof(d3), xv, acc[6]); acc[7] = fmaf(hif(d3), xv, acc[7]);    \
  }

#define MV16(M)                                                                \
  MV_STEP(M, 0)  MV_STEP(M, 1)  MV_STEP(M, 2)  MV_STEP(M, 3)                  \
  MV_STEP(M, 4)  MV_STEP(M, 5)  MV_STEP(M, 6)  MV_STEP(M, 7)                  \
  MV_STEP(M, 8)  MV_STEP(M, 9)  MV_STEP(M, 10) MV_STEP(M, 11)                 \
  MV_STEP(M, 12) MV_STEP(M, 13) MV_STEP(M, 14) MV_STEP(M, 15)

// One full phase: build x -> matvec from AGPR weights -> block-level column
// reduce -> write partials. TM = t-row AGPR prefix, COEF = t-row coefficient.
#define RUN_PHASE(MODE, M, TM, PIN, POUT, CPART, COEF, RKI)                    \
  {                                                                            \
    build_x((MODE), (PIN), (CPART), u1, fcur, fprev, ycur, ksum, rk, (RKI),    \
            s, csv, dtv, xs, red, tid, cb, rc, j0);                            \
    float acc[8] = {0.f, 0.f, 0.f, 0.f, 0.f, 0.f, 0.f, 0.f};                   \
    MV16(M)                                                                    \
    if (doT) {                                                                 \
      unsigned d0, d1, d2, d3;                                                 \
      AR(d0, TM##_0); AR(d1, TM##_1); AR(d2, TM##_2); AR(d3, TM##_3);          \
      const float cf = (COEF);                                                 \
      acc[0] = fmaf(lof(d0), cf, acc[0]); acc[1] = fmaf(hif(d0), cf, acc[1]);  \
      acc[2] = fmaf(lof(d1), cf, acc[2]); acc[3] = fmaf(hif(d1), cf, acc[3]);  \
      acc[4] = fmaf(lof(d2), cf, acc[4]); acc[5] = fmaf(hif(d2), cf, acc[5]);  \
      acc[6] = fmaf(lof(d3), cf, acc[6]); acc[7] = fmaf(hif(d3), cf, acc[7]);  \
    }                                                                          \
    _Pragma("unroll")                                                          \
    for (int e = 0; e < 8; ++e) red[rg][cg * 8 + e] = acc[e];                  \
    __syncthreads();                                                           \
    float ssum = 0.f;                                                          \
    _Pragma("unroll")                                                          \
    for (int g = 0; g < 8; ++g) ssum += red[g][tid];                           \
    (POUT)[(rc << 12) + cb * 256 + tid] = ssum;                                \
  }

// ---------------------------------------------------------------------------
__global__ __launch_bounds__(TPB)
__attribute__((amdgpu_waves_per_eu(2, 2)))
void k_ode(
    const float* __restrict__ W1f, const float* __restrict__ W2f,
    const float* __restrict__ tptr,
    float* __restrict__ partA, float* __restrict__ partB,
    const float* __restrict__ cp1, const float* __restrict__ cp2,
    float* __restrict__ u1, float* __restrict__ fb0, float* __restrict__ fb1,
    float* __restrict__ ycur, float* __restrict__ ksum,
    float* __restrict__ rk, unsigned* flags) {
  __shared__ float xs[128];
  __shared__ float red[8][256];
  const int tid = threadIdx.x;
  const int bid = blockIdx.x;
  const int cb = bid & 15, rc = bid >> 4;
  const int j0 = rc * 128;
  const int cg = tid & 31, rg = tid >> 5;
  unsigned* go = flags + 512;

  // ---- one-time: fp32 -> bf16 (RNE) weight tiles into AGPRs ----
  const size_t colOff = (size_t)(cb * 256 + cg * 8);
  const float* __restrict__ w1p = W1f + (size_t)(NC + j0 + rg) * N + colOff;
  const float* __restrict__ w2p = W2f + (size_t)(NC + j0 + rg) * N + colOff;

  DECL4(g1_0)  DECL4(g1_1)  DECL4(g1_2)  DECL4(g1_3)
  DECL4(g1_4)  DECL4(g1_5)  DECL4(g1_6)  DECL4(g1_7)
  DECL4(g1_8)  DECL4(g1_9)  DECL4(g1_10) DECL4(g1_11)
  DECL4(g1_12) DECL4(g1_13) DECL4(g1_14) DECL4(g1_15)
  DECL4(g2_0)  DECL4(g2_1)  DECL4(g2_2)  DECL4(g2_3)
  DECL4(g2_4)  DECL4(g2_5)  DECL4(g2_6)  DECL4(g2_7)
  DECL4(g2_8)  DECL4(g2_9)  DECL4(g2_10) DECL4(g2_11)
  DECL4(g2_12) DECL4(g2_13) DECL4(g2_14) DECL4(g2_15)
  DECL4(t1) DECL4(t2)

  LDW(g1, 0, w1p)  LDW(g1, 1, w1p)  LDW(g1, 2, w1p)  LDW(g1, 3, w1p)
  LDW(g1, 4, w1p)  LDW(g1, 5, w1p)  LDW(g1, 6, w1p)  LDW(g1, 7, w1p)
  LDW(g1, 8, w1p)  LDW(g1, 9, w1p)  LDW(g1, 10, w1p) LDW(g1, 11, w1p)
  LDW(g1, 12, w1p) LDW(g1, 13, w1p) LDW(g1, 14, w1p) LDW(g1, 15, w1p)
  LDW(g2, 0, w2p)  LDW(g2, 1, w2p)  LDW(g2, 2, w2p)  LDW(g2, 3, w2p)
  LDW(g2, 4, w2p)  LDW(g2, 5, w2p)  LDW(g2, 6, w2p)  LDW(g2, 7, w2p)
  LDW(g2, 8, w2p)  LDW(g2, 9, w2p)  LDW(g2, 10, w2p) LDW(g2, 11, w2p)
  LDW(g2, 12, w2p) LDW(g2, 13, w2p) LDW(g2, 14, w2p) LDW(g2, 15, w2p)

  // t-row (row NC+N) — loaded by every thread (uniform, cheap), used by doT.
  {
    const float* tp1 = W1f + (size_t)(NC + N) * N + colOff;
    const float* tp2 = W2f + (size_t)(NC + N) * N + colOff;
    const uint4 q1 = __builtin_bit_cast(
        uint4, cvt8(*reinterpret_cast<const float4*>(tp1),
                    *reinterpret_cast<const float4*>(tp1 + 4)));
    AW(t1_0, q1.x); AW(t1_1, q1.y); AW(t1_2, q1.z); AW(t1_3, q1.w);
    const uint4 q2 = __builtin_bit_cast(
        uint4, cvt8(*reinterpret_cast<const float4*>(tp2),
                    *reinterpret_cast<const float4*>(tp2 + 4)));
    AW(t2_0, q2.x); AW(t2_1, q2.y); AW(t2_2, q2.z); AW(t2_3, q2.w);
  }
  const bool doT = (rc == 31 && rg == 0);
  const float dtv = tptr[0] * (1.0f / STEPS);

  // ---- 16 evals x 4 phases, grid sync between phases ----
  float* pA = partA;
  float* pB = partB;
  unsigned sn = 0;

  for (int i = 0; i < 16; ++i) {
    const int s = i & 3;
    const float csv = (s == 0) ? 0.f : ((s == 3) ? 1.f : 0.5f);
    const float tcoef = ((float)(i >> 2) + csv) * dtv;
    float* fcur = (i & 1) ? fb1 : fb0;
    const float* fprev = (i & 1) ? fb0 : fb1;

    // P1: u1 partials = x1 @ W1_state (FIRST for i=0, PD otherwise)
    RUN_PHASE((i == 0) ? 0 : 4, g1, t1, pB, pA, cp1, tcoef, i - 1)
    { float* tp = pA; pA = pB; pB = tp; }
    ++sn; gsync(flags, go, sn, bid, tid);

    // P2: f partials = sig(u1+cp1) @ W2_state
    RUN_PHASE(1, g2, t2, pB, pA, cp1, tcoef, 0)
    { float* tp = pA; pA = pB; pB = tp; }
    ++sn; gsync(flags, go, sn, bid, tid);

    // P3: du1 partials = (sig'(ys)*f) @ W1_state, t-coef 1
    RUN_PHASE(2, g1, t1, pB, pA, cp2, 1.f, 0)
    { float* tp = pA; pA = pB; pB = tp; }
    ++sn; gsync(flags, go, sn, bid, tid);

    // P4: df partials = (sig'(u1)*du1) @ W2_state, t-coef 1; RK bookkeeping
    RUN_PHASE(3, g2, t2, pB, pA, cp2, 1.f, 0)
    { float* tp = pA; pA = pB; pB = tp; }
    if (i < 15) { ++sn; gsync(flags, go, sn, bid, tid); }
  }
}

// Reduce the final P4 partials -> rk[15]; copy ycur -> out.
__global__ __launch_bounds__(128) void k_last(const float* __restrict__ part_in,
                                              const float* __restrict__ ycur,
                                              float* __restrict__ rk,
                                              float* __restrict__ out) {
  const int tid = threadIdx.x;
  const int j = blockIdx.x * 128 + tid;
  float df = 0.f;
#pragma unroll 8
  for (int r = 0; r < 32; ++r) df += part_in[(r << 12) + j];
  float v = df * df;
#pragma unroll
  for (int off = 32; off >= 1; off >>= 1) v += __shfl_down(v, off);
  if ((tid & 63) == 0) atomicAdd(&rk[15], v);
  out[j] = ycur[j];
}

__global__ void k_out(const float* __restrict__ rk, const float* __restrict__ tptr,
                      float* __restrict__ out) {
  if (threadIdx.x == 0) {
    const float dtv = tptr[0] * (1.0f / STEPS);
    float r = 0.f;
    for (int st = 0; st < STEPS; ++st)
      r += rk[4 * st] + 2.f * rk[4 * st + 1] + 2.f * rk[4 * st + 2] + rk[4 * st + 3];
    out[N] = r * (dtv / 6.f) * (1.0f / N);
  }
}

// ---------------------------------------------------------------------------
extern "C" void kernel_launch(void* const* d_in, const int* in_sizes, int n_in,
                              void* d_out, int out_size, void* d_ws, size_t ws_size,
                              hipStream_t stream) {
  const float* h  = (const float*)d_in[0];
  const float* t  = (const float*)d_in[1];
  const float* c  = (const float*)d_in[2];
  const float* W1 = (const float*)d_in[3];
  const float* b1 = (const float*)d_in[4];
  const float* W2 = (const float*)d_in[5];
  const float* b2 = (const float*)d_in[6];
  float* out = (float*)d_out;

  // ws: fp32 buffers + flags (~1.2 MB) — weights live in AGPRs.
  float* fp    = (float*)d_ws;
  float* partA = fp;                     // 32*4096
  float* partB = partA + 32 * N;
  float* cp1   = partB + 32 * N;
  float* cp2   = cp1 + N;
  float* u1    = cp2 + N;
  float* fb0   = u1 + N;
  float* fb1   = fb0 + N;
  float* ycur  = fb1 + N;
  float* ksum  = ycur + N;
  float* rk    = ksum + N;               // 16
  unsigned* flags = (unsigned*)(rk + 16); // 512 flags + go + pad

  k_init<<<16, TPB, 0, stream>>>(h, b1, b2, ycur, cp1, cp2, rk, flags);
  k_cpart<<<dim3(16, 8, 2), TPB, 0, stream>>>(W1, W2, c, cp1, cp2);

  k_ode<<<NBLK, TPB, 0, stream>>>(W1, W2, t, partA, partB, cp1, cp2,
                                  u1, fb0, fb1, ycur, ksum, rk, flags);

  k_last<<<32, 128, 0, stream>>>(partB, ycur, rk, out);
  k_out<<<1, 64, 0, stream>>>(rk, t, out);
}

// Round 8
// 1764.340 us; speedup vs baseline: 2.3961x; 2.2093x over previous
//
#include <hip/hip_runtime.h>

// STATE=4096, CDIM=1024, fan_in=5121. RK4 x 4 steps = 16 aug-dynamics evals
// = 64 matvec phases. Persistent kernel: both 4096x4096 weight matrices live
// in AGPRs, pinned by inline asm (v_accvgpr_write/read) — round 7 verified
// this kills the spill traffic (FETCH 1.27GB -> 0.54GB). Round-7 lesson:
// agent-scope ACQUIRE spin-loads lower to global_load + buffer_inv sc1 (full
// per-XCD L2 invalidate) EVERY iteration -> invalidation storm -> 58us per
// grid barrier = the whole 3.7ms. Fix: RELAXED spin loads (scope bits on the
// load read the coherent point; no cache op), then ONE acquire load after
// the value is observed (single buffer_inv per wave per barrier).
#define N      4096
#define NC     1024
#define STEPS  4
#define TPB    256
#define NBLK   512

typedef unsigned short us8 __attribute__((ext_vector_type(8)));

__device__ __forceinline__ float bf2f(unsigned short u) {
  union { unsigned int i; float f; } v; v.i = ((unsigned int)u) << 16; return v.f;
}
__device__ __forceinline__ unsigned short f2bf(float f) {
  union { float f; unsigned int i; } v; v.f = f;
  const unsigned int u = v.i;
  return (unsigned short)((u + 0x7FFFu + ((u >> 16) & 1u)) >> 16);  // RNE
}
__device__ __forceinline__ float sigf(float x) { return 1.0f / (1.0f + __expf(-x)); }
__device__ __forceinline__ us8 cvt8(const float4 a, const float4 b) {
  us8 o;
  o[0] = f2bf(a.x); o[1] = f2bf(a.y); o[2] = f2bf(a.z); o[3] = f2bf(a.w);
  o[4] = f2bf(b.x); o[5] = f2bf(b.y); o[6] = f2bf(b.z); o[7] = f2bf(b.w);
  return o;
}
// bf16 pair extraction from a packed dword — bit-identical to bf2f of each u16
__device__ __forceinline__ float lof(unsigned d) {
  union { unsigned u; float f; } v; v.u = d << 16; return v.f;
}
__device__ __forceinline__ float hif(unsigned d) {
  union { unsigned u; float f; } v; v.u = d & 0xffff0000u; return v.f;
}

// AGPR pin/read. Volatile: not sinkable/hoistable/CSE-able/remat-able.
#define AW(dst, src) \
  asm volatile("v_accvgpr_write_b32 %0, %1" : "=a"(dst) : "v"(src))
#define AR(dst, src) \
  asm volatile("v_accvgpr_read_b32 %0, %1" : "=v"(dst) : "a"(src))

// ---------------------------------------------------------------------------
__global__ __launch_bounds__(TPB) void k_init(const float* __restrict__ h,
                                              const float* __restrict__ b1,
                                              const float* __restrict__ b2,
                                              float* __restrict__ ycur,
                                              float* __restrict__ cp1,
                                              float* __restrict__ cp2,
                                              float* __restrict__ rk,
                                              unsigned* __restrict__ flags) {
  const int j = blockIdx.x * TPB + threadIdx.x;
  if (j < N) { ycur[j] = h[j]; cp1[j] = b1[j]; cp2[j] = b2[j]; }
  if (j < 16) rk[j] = 0.f;
  if (j < 544) flags[j] = 0u;   // 512 arrive-flags + go + pad; re-zero per replay
}

// cp += c @ W[0:NC]  (fp32, once). grid (16, 8, 2), block 256.
__global__ __launch_bounds__(TPB) void k_cpart(const float* __restrict__ W1,
                                               const float* __restrict__ W2,
                                               const float* __restrict__ c,
                                               float* __restrict__ cp1,
                                               float* __restrict__ cp2) {
  const float* __restrict__ W = blockIdx.z ? W2 : W1;
  float* __restrict__ cp = blockIdx.z ? cp2 : cp1;
  __shared__ float xs[128];
  __shared__ float red[8][256];
  const int tid = threadIdx.x;
  const int cb = blockIdx.x, rc = blockIdx.y;
  const int r0 = rc * 128;
  if (tid < 128) xs[tid] = c[r0 + tid];
  __syncthreads();
  const int cg = tid & 31, rg = tid >> 5;
  const float* __restrict__ wbase = W + (size_t)r0 * N + cb * 256 + cg * 8;
  float a[8] = {0,0,0,0,0,0,0,0};
#pragma unroll
  for (int k = 0; k < 16; ++k) {
    const int r = rg + (k << 3);
    const float xv = xs[r];
    const float4 wa = *reinterpret_cast<const float4*>(wbase + (size_t)r * N);
    const float4 wb = *reinterpret_cast<const float4*>(wbase + (size_t)r * N + 4);
    a[0] = fmaf(wa.x, xv, a[0]); a[1] = fmaf(wa.y, xv, a[1]);
    a[2] = fmaf(wa.z, xv, a[2]); a[3] = fmaf(wa.w, xv, a[3]);
    a[4] = fmaf(wb.x, xv, a[4]); a[5] = fmaf(wb.y, xv, a[5]);
    a[6] = fmaf(wb.z, xv, a[6]); a[7] = fmaf(wb.w, xv, a[7]);
  }
#pragma unroll
  for (int e = 0; e < 8; ++e) red[rg][cg * 8 + e] = a[e];
  __syncthreads();
  float ssum = 0.f;
#pragma unroll
  for (int g = 0; g < 8; ++g) ssum += red[g][tid];
  atomicAdd(&cp[cb * 256 + tid], ssum);
}

// ---------------------------------------------------------------------------
// Grid barrier, monotonic rounds. Writers: release-store flag[bid]=round
// (one buffer_wbl2 per block — needed to publish partials anyway).
// Spins are RELAXED (no cache-maintenance per iteration); after the spin
// observes the value, ONE acquire load re-reads it to create the
// synchronizes-with edge (single buffer_inv per wave per barrier).
__device__ __forceinline__ void gsync(unsigned* flags, unsigned* go,
                                      const unsigned round,
                                      const int bid, const int tid) {
  __syncthreads();
  if (bid == 0) {
    if (tid == 0)
      __hip_atomic_store(&flags[0], round, __ATOMIC_RELEASE, __HIP_MEMORY_SCOPE_AGENT);
    while (__hip_atomic_load(&flags[tid], __ATOMIC_RELAXED, __HIP_MEMORY_SCOPE_AGENT) < round ||
           __hip_atomic_load(&flags[tid + 256], __ATOMIC_RELAXED, __HIP_MEMORY_SCOPE_AGENT) < round) {
      __builtin_amdgcn_s_sleep(2);
    }
    // acquire pass: sync-edge with each observed release store
    while (__hip_atomic_load(&flags[tid], __ATOMIC_ACQUIRE, __HIP_MEMORY_SCOPE_AGENT) < round) {}
    while (__hip_atomic_load(&flags[tid + 256], __ATOMIC_ACQUIRE, __HIP_MEMORY_SCOPE_AGENT) < round) {}
    __syncthreads();
    if (tid == 0)
      __hip_atomic_store(go, round, __ATOMIC_RELEASE, __HIP_MEMORY_SCOPE_AGENT);
  } else {
    if (tid == 0) {
      __hip_atomic_store(&flags[bid], round, __ATOMIC_RELEASE, __HIP_MEMORY_SCOPE_AGENT);
      while (__hip_atomic_load(go, __ATOMIC_RELAXED, __HIP_MEMORY_SCOPE_AGENT) < round) {
        __builtin_amdgcn_s_sleep(2);
      }
      while (__hip_atomic_load(go, __ATOMIC_ACQUIRE, __HIP_MEMORY_SCOPE_AGENT) < round) {}
    }
    __syncthreads();
  }
}

// ---------------------------------------------------------------------------
// Epilogue of previous phase + build x chunk (everything except the matvec).
// Modes: 0=FIRST(x=sig(h)), 1=P2(u1), 2=P3(f,tangent-L1 in), 3=P4(du1,RK),
//        4=PD(df,rk,next-stage x1).
// ---------------------------------------------------------------------------
__device__ __forceinline__ void build_x(
    const int mode,
    const float* __restrict__ pin, const float* __restrict__ cpart,
    float* __restrict__ u1, float* __restrict__ fcur,
    const float* __restrict__ fprev,
    float* __restrict__ ycur, float* __restrict__ ksum,
    float* __restrict__ rk, const int rkIdx, const int s,
    const float csv, const float dtv,
    float (&xs)[128], float (&red)[8][256],
    const int tid, const int cb, const int rc, const int j0) {
  // partial reduce split across all 256 threads (red[0..1][0..127] reused)
  if (mode != 0) {
    const int jl = tid & 127, half = tid >> 7;
    const float* __restrict__ pp = pin + ((half << 4) << 12) + j0 + jl;
    float ps = 0.f;
#pragma unroll
    for (int r = 0; r < 16; ++r) ps += pp[(size_t)(r << 12)];
    red[half][jl] = ps;
  }
  __syncthreads();

  if (tid < 128) {
    const int j = j0 + tid;
    float xv;
    if (mode == 0) {                       // FIRST: x1 = sig(h)
      xv = sigf(ycur[j]);
    } else {
      const float ssum = red[0][tid] + red[1][tid];
      if (mode == 1) {                     // P2: u1 = red + cpart1; x2 = sig(u1)
        const float u = ssum + cpart[j];
        if (cb == 0) u1[j] = u;
        xv = sigf(u);
      } else if (mode == 2) {              // P3: f = red + cpart2; v1 = s0'(ys)*f
        const float fv = ssum + cpart[j];
        if (cb == 0) fcur[j] = fv;
        float ys = ycur[j];
        if (csv != 0.f) ys = fmaf(csv * dtv, fprev[j], ys);
        const float s0 = sigf(ys);
        xv = s0 * (1.f - s0) * fv;
      } else if (mode == 3) {              // P4: du1 = red; v2 = s1'(u1)*du1; RK
        if (cb == 0) {
          const float fc = fcur[j];
          if (s == 0)      ksum[j] = fc;
          else if (s < 3)  ksum[j] = fmaf(2.f, fc, ksum[j]);
          else             ycur[j] = fmaf(dtv * (1.f / 6.f), ksum[j] + fc, ycur[j]);
        }
        const float s1 = sigf(u1[j]);
        xv = s1 * (1.f - s1) * ssum;
      } else {                             // PD: df = red; rk += df^2; x1 next
        float v = ssum * ssum;
#pragma unroll
        for (int off = 32; off >= 1; off >>= 1) v += __shfl_down(v, off);
        if (cb == 0 && (tid & 63) == 0) atomicAdd(&rk[rkIdx], v);
        float ys = ycur[j];
        if (csv != 0.f) ys = fmaf(csv * dtv, fprev[j], ys);
        xv = sigf(ys);
      }
    }
    xs[tid] = xv;
  }
  __syncthreads();
}

// ---------------------------------------------------------------------------
// AGPR weight storage: 4 dwords per 16-row step, 16 steps per matrix.
#define DECL4(P) unsigned P##_0, P##_1, P##_2, P##_3;

#define LDW(M, K, SRCP)                                                        \
  {                                                                            \
    const size_t off = (size_t)(K << 3) * N;                                   \
    const uint4 q = __builtin_bit_cast(                                        \
        uint4, cvt8(*reinterpret_cast<const float4*>((SRCP) + off),            \
                    *reinterpret_cast<const float4*>((SRCP) + off + 4)));      \
    AW(M##_##K##_0, q.x); AW(M##_##K##_1, q.y);                                \
    AW(M##_##K##_2, q.z); AW(M##_##K##_3, q.w);                                \
  }

#define MV_STEP(M, K)                                                          \
  {                                                                            \
    const float xv = xs[rg + (K << 3)];                                        \
    unsigned d0, d1, d2, d3;                                                   \
    AR(d0, M##_##K##_0); AR(d1, M##_##K##_1);                                  \
    AR(d2, M##_##K##_2); AR(d3, M##_##K##_3);                                  \
    acc[0] = fmaf(lof(d0), xv, acc[0]); acc[1] = fmaf(hif(d0), xv, acc[1]);    \
    acc[2] = fmaf(lof(d1), xv, acc[2]); acc[3] = fmaf(hif(d1), xv, acc[3]);    \
    acc[4] = fmaf(lof(d2), xv, acc[4]); acc[5] = fmaf(hif(d2), xv, acc[5]);    \
    acc[6] = fmaf(lof(d3), xv, acc[6]); acc[7] = fmaf(hif(d3), xv, acc[7]);    \
  }

#define MV16(M)                                                                \
  MV_STEP(M, 0)  MV_STEP(M, 1)  MV_STEP(M, 2)  MV_STEP(M, 3)                  \
  MV_STEP(M, 4)  MV_STEP(M, 5)  MV_STEP(M, 6)  MV_STEP(M, 7)                  \
  MV_STEP(M, 8)  MV_STEP(M, 9)  MV_STEP(M, 10) MV_STEP(M, 11)                 \
  MV_STEP(M, 12) MV_STEP(M, 13) MV_STEP(M, 14) MV_STEP(M, 15)

// One full phase: build x -> matvec from AGPR weights -> block-level column
// reduce -> write partials. TM = t-row AGPR prefix, COEF = t-row coefficient.
#define RUN_PHASE(MODE, M, TM, PIN, POUT, CPART, COEF, RKI)                    \
  {                                                                            \
    build_x((MODE), (PIN), (CPART), u1, fcur, fprev, ycur, ksum, rk, (RKI),    \
            s, csv, dtv, xs, red, tid, cb, rc, j0);                            \
    float acc[8] = {0.f, 0.f, 0.f, 0.f, 0.f, 0.f, 0.f, 0.f};                   \
    MV16(M)                                                                    \
    if (doT) {                                                                 \
      unsigned d0, d1, d2, d3;                                                 \
      AR(d0, TM##_0); AR(d1, TM##_1); AR(d2, TM##_2); AR(d3, TM##_3);          \
      const float cf = (COEF);                                                 \
      acc[0] = fmaf(lof(d0), cf, acc[0]); acc[1] = fmaf(hif(d0), cf, acc[1]);  \
      acc[2] = fmaf(lof(d1), cf, acc[2]); acc[3] = fmaf(hif(d1), cf, acc[3]);  \
      acc[4] = fmaf(lof(d2), cf, acc[4]); acc[5] = fmaf(hif(d2), cf, acc[5]);  \
      acc[6] = fmaf(lof(d3), cf, acc[6]); acc[7] = fmaf(hif(d3), cf, acc[7]);  \
    }                                                                          \
    _Pragma("unroll")                                                          \
    for (int e = 0; e < 8; ++e) red[rg][cg * 8 + e] = acc[e];                  \
    __syncthreads();                                                           \
    float ssum = 0.f;                                                          \
    _Pragma("unroll")                                                          \
    for (int g = 0; g < 8; ++g) ssum += red[g][tid];                           \
    (POUT)[(rc << 12) + cb * 256 + tid] = ssum;                                \
  }

// ---------------------------------------------------------------------------
__global__ __launch_bounds__(TPB)
__attribute__((amdgpu_waves_per_eu(2, 2)))
void k_ode(
    const float* __restrict__ W1f, const float* __restrict__ W2f,
    const float* __restrict__ tptr,
    float* __restrict__ partA, float* __restrict__ partB,
    const float* __restrict__ cp1, const float* __restrict__ cp2,
    float* __restrict__ u1, float* __restrict__ fb0, float* __restrict__ fb1,
    float* __restrict__ ycur, float* __restrict__ ksum,
    float* __restrict__ rk, unsigned* flags) {
  __shared__ float xs[128];
  __shared__ float red[8][256];
  const int tid = threadIdx.x;
  const int bid = blockIdx.x;
  const int cb = bid & 15, rc = bid >> 4;
  const int j0 = rc * 128;
  const int cg = tid & 31, rg = tid >> 5;
  unsigned* go = flags + 512;

  // ---- one-time: fp32 -> bf16 (RNE) weight tiles into AGPRs ----
  const size_t colOff = (size_t)(cb * 256 + cg * 8);
  const float* __restrict__ w1p = W1f + (size_t)(NC + j0 + rg) * N + colOff;
  const float* __restrict__ w2p = W2f + (size_t)(NC + j0 + rg) * N + colOff;

  DECL4(g1_0)  DECL4(g1_1)  DECL4(g1_2)  DECL4(g1_3)
  DECL4(g1_4)  DECL4(g1_5)  DECL4(g1_6)  DECL4(g1_7)
  DECL4(g1_8)  DECL4(g1_9)  DECL4(g1_10) DECL4(g1_11)
  DECL4(g1_12) DECL4(g1_13) DECL4(g1_14) DECL4(g1_15)
  DECL4(g2_0)  DECL4(g2_1)  DECL4(g2_2)  DECL4(g2_3)
  DECL4(g2_4)  DECL4(g2_5)  DECL4(g2_6)  DECL4(g2_7)
  DECL4(g2_8)  DECL4(g2_9)  DECL4(g2_10) DECL4(g2_11)
  DECL4(g2_12) DECL4(g2_13) DECL4(g2_14) DECL4(g2_15)
  DECL4(t1) DECL4(t2)

  LDW(g1, 0, w1p)  LDW(g1, 1, w1p)  LDW(g1, 2, w1p)  LDW(g1, 3, w1p)
  LDW(g1, 4, w1p)  LDW(g1, 5, w1p)  LDW(g1, 6, w1p)  LDW(g1, 7, w1p)
  LDW(g1, 8, w1p)  LDW(g1, 9, w1p)  LDW(g1, 10, w1p) LDW(g1, 11, w1p)
  LDW(g1, 12, w1p) LDW(g1, 13, w1p) LDW(g1, 14, w1p) LDW(g1, 15, w1p)
  LDW(g2, 0, w2p)  LDW(g2, 1, w2p)  LDW(g2, 2, w2p)  LDW(g2, 3, w2p)
  LDW(g2, 4, w2p)  LDW(g2, 5, w2p)  LDW(g2, 6, w2p)  LDW(g2, 7, w2p)
  LDW(g2, 8, w2p)  LDW(g2, 9, w2p)  LDW(g2, 10, w2p) LDW(g2, 11, w2p)
  LDW(g2, 12, w2p) LDW(g2, 13, w2p) LDW(g2, 14, w2p) LDW(g2, 15, w2p)

  // t-row (row NC+N) — loaded by every thread (uniform, cheap), used by doT.
  {
    const float* tp1 = W1f + (size_t)(NC + N) * N + colOff;
    const float* tp2 = W2f + (size_t)(NC + N) * N + colOff;
    const uint4 q1 = __builtin_bit_cast(
        uint4, cvt8(*reinterpret_cast<const float4*>(tp1),
                    *reinterpret_cast<const float4*>(tp1 + 4)));
    AW(t1_0, q1.x); AW(t1_1, q1.y); AW(t1_2, q1.z); AW(t1_3, q1.w);
    const uint4 q2 = __builtin_bit_cast(
        uint4, cvt8(*reinterpret_cast<const float4*>(tp2),
                    *reinterpret_cast<const float4*>(tp2 + 4)));
    AW(t2_0, q2.x); AW(t2_1, q2.y); AW(t2_2, q2.z); AW(t2_3, q2.w);
  }
  const bool doT = (rc == 31 && rg == 0);
  const float dtv = tptr[0] * (1.0f / STEPS);

  // ---- 16 evals x 4 phases, grid sync between phases ----
  float* pA = partA;
  float* pB = partB;
  unsigned sn = 0;

  for (int i = 0; i < 16; ++i) {
    const int s = i & 3;
    const float csv = (s == 0) ? 0.f : ((s == 3) ? 1.f : 0.5f);
    const float tcoef = ((float)(i >> 2) + csv) * dtv;
    float* fcur = (i & 1) ? fb1 : fb0;
    const float* fprev = (i & 1) ? fb0 : fb1;

    // P1: u1 partials = x1 @ W1_state (FIRST for i=0, PD otherwise)
    RUN_PHASE((i == 0) ? 0 : 4, g1, t1, pB, pA, cp1, tcoef, i - 1)
    { float* tp = pA; pA = pB; pB = tp; }
    ++sn; gsync(flags, go, sn, bid, tid);

    // P2: f partials = sig(u1+cp1) @ W2_state
    RUN_PHASE(1, g2, t2, pB, pA, cp1, tcoef, 0)
    { float* tp = pA; pA = pB; pB = tp; }
    ++sn; gsync(flags, go, sn, bid, tid);

    // P3: du1 partials = (sig'(ys)*f) @ W1_state, t-coef 1
    RUN_PHASE(2, g1, t1, pB, pA, cp2, 1.f, 0)
    { float* tp = pA; pA = pB; pB = tp; }
    ++sn; gsync(flags, go, sn, bid, tid);

    // P4: df partials = (sig'(u1)*du1) @ W2_state, t-coef 1; RK bookkeeping
    RUN_PHASE(3, g2, t2, pB, pA, cp2, 1.f, 0)
    { float* tp = pA; pA = pB; pB = tp; }
    if (i < 15) { ++sn; gsync(flags, go, sn, bid, tid); }
  }
}

// Reduce the final P4 partials -> rk[15]; copy ycur -> out.
__global__ __launch_bounds__(128) void k_last(const float* __restrict__ part_in,
                                              const float* __restrict__ ycur,
                                              float* __restrict__ rk,
                                              float* __restrict__ out) {
  const int tid = threadIdx.x;
  const int j = blockIdx.x * 128 + tid;
  float df = 0.f;
#pragma unroll 8
  for (int r = 0; r < 32; ++r) df += part_in[(r << 12) + j];
  float v = df * df;
#pragma unroll
  for (int off = 32; off >= 1; off >>= 1) v += __shfl_down(v, off);
  if ((tid & 63) == 0) atomicAdd(&rk[15], v);
  out[j] = ycur[j];
}

__global__ void k_out(const float* __restrict__ rk, const float* __restrict__ tptr,
                      float* __restrict__ out) {
  if (threadIdx.x == 0) {
    const float dtv = tptr[0] * (1.0f / STEPS);
    float r = 0.f;
    for (int st = 0; st < STEPS; ++st)
      r += rk[4 * st] + 2.f * rk[4 * st + 1] + 2.f * rk[4 * st + 2] + rk[4 * st + 3];
    out[N] = r * (dtv / 6.f) * (1.0f / N);
  }
}

// ---------------------------------------------------------------------------
extern "C" void kernel_launch(void* const* d_in, const int* in_sizes, int n_in,
                              void* d_out, int out_size, void* d_ws, size_t ws_size,
                              hipStream_t stream) {
  const float* h  = (const float*)d_in[0];
  const float* t  = (const float*)d_in[1];
  const float* c  = (const float*)d_in[2];
  const float* W1 = (const float*)d_in[3];
  const float* b1 = (const float*)d_in[4];
  const float* W2 = (const float*)d_in[5];
  const float* b2 = (const float*)d_in[6];
  float* out = (float*)d_out;

  // ws: fp32 buffers + flags (~1.2 MB) — weights live in AGPRs.
  float* fp    = (float*)d_ws;
  float* partA = fp;                     // 32*4096
  float* partB = partA + 32 * N;
  float* cp1   = partB + 32 * N;
  float* cp2   = cp1 + N;
  float* u1    = cp2 + N;
  float* fb0   = u1 + N;
  float* fb1   = fb0 + N;
  float* ycur  = fb1 + N;
  float* ksum  = ycur + N;
  float* rk    = ksum + N;               // 16
  unsigned* flags = (unsigned*)(rk + 16); // 512 flags + go + pad

  k_init<<<16, TPB, 0, stream>>>(h, b1, b2, ycur, cp1, cp2, rk, flags);
  k_cpart<<<dim3(16, 8, 2), TPB, 0, stream>>>(W1, W2, c, cp1, cp2);

  k_ode<<<NBLK, TPB, 0, stream>>>(W1, W2, t, partA, partB, cp1, cp2,
                                  u1, fb0, fb1, ycur, ksum, rk, flags);

  k_last<<<32, 128, 0, stream>>>(partB, ycur, rk, out);
  k_out<<<1, 64, 0, stream>>>(rk, t, out);
}

// Round 9
// 1040.111 us; speedup vs baseline: 4.0645x; 1.6963x over previous
//
#include <hip/hip_runtime.h>

// STATE=4096, CDIM=1024, fan_in=5121. RK4 x 4 steps = 16 aug-dynamics evals
// = 64 matvec phases. Persistent kernel, weights pinned in AGPRs (r7: kills
// spill traffic). Barrier evolution: r7 acquire-spin -> buffer_inv per spin
// iteration (58us/barrier). r8 relaxed-spin + final acquire -> still ~26us:
// ~513 buffer_wbl2 (release stores) + ~519 buffer_inv (acquire passes) per
// barrier, TCC-serialized. r9 fix: NO acquire/release anywhere. All
// cross-block data moves via agent-scope RELAXED atomics = sc1 accesses that
// bypass the non-coherent per-XCD L2 and hit L3 (coherent point) directly.
// Zero cache-maintenance ops. Ordering: __syncthreads drains vmcnt(0) before
// s_barrier (compiler-guaranteed), so partial stores are L3-acked before the
// arrival flag store; compiler barriers stop load hoisting above spins.
#define N      4096
#define NC     1024
#define STEPS  4
#define TPB    256
#define NBLK   512

typedef unsigned short us8 __attribute__((ext_vector_type(8)));

// Agent-scope relaxed = sc1 (L2-bypass, L3-coherent), no cache ops.
#define LDC(p)    __hip_atomic_load((p), __ATOMIC_RELAXED, __HIP_MEMORY_SCOPE_AGENT)
#define STC(p, v) __hip_atomic_store((p), (v), __ATOMIC_RELAXED, __HIP_MEMORY_SCOPE_AGENT)

__device__ __forceinline__ float bf2f(unsigned short u) {
  union { unsigned int i; float f; } v; v.i = ((unsigned int)u) << 16; return v.f;
}
__device__ __forceinline__ unsigned short f2bf(float f) {
  union { float f; unsigned int i; } v; v.f = f;
  const unsigned int u = v.i;
  return (unsigned short)((u + 0x7FFFu + ((u >> 16) & 1u)) >> 16);  // RNE
}
__device__ __forceinline__ float sigf(float x) { return 1.0f / (1.0f + __expf(-x)); }
__device__ __forceinline__ us8 cvt8(const float4 a, const float4 b) {
  us8 o;
  o[0] = f2bf(a.x); o[1] = f2bf(a.y); o[2] = f2bf(a.z); o[3] = f2bf(a.w);
  o[4] = f2bf(b.x); o[5] = f2bf(b.y); o[6] = f2bf(b.z); o[7] = f2bf(b.w);
  return o;
}
// bf16 pair extraction from a packed dword — bit-identical to bf2f of each u16
__device__ __forceinline__ float lof(unsigned d) {
  union { unsigned u; float f; } v; v.u = d << 16; return v.f;
}
__device__ __forceinline__ float hif(unsigned d) {
  union { unsigned u; float f; } v; v.u = d & 0xffff0000u; return v.f;
}

// AGPR pin/read. Volatile: not sinkable/hoistable/CSE-able/remat-able.
#define AW(dst, src) \
  asm volatile("v_accvgpr_write_b32 %0, %1" : "=a"(dst) : "v"(src))
#define AR(dst, src) \
  asm volatile("v_accvgpr_read_b32 %0, %1" : "=v"(dst) : "a"(src))

// ---------------------------------------------------------------------------
__global__ __launch_bounds__(TPB) void k_init(const float* __restrict__ h,
                                              const float* __restrict__ b1,
                                              const float* __restrict__ b2,
                                              float* __restrict__ ycur,
                                              float* __restrict__ cp1,
                                              float* __restrict__ cp2,
                                              float* __restrict__ rk,
                                              unsigned* __restrict__ flags) {
  const int j = blockIdx.x * TPB + threadIdx.x;
  if (j < N) { ycur[j] = h[j]; cp1[j] = b1[j]; cp2[j] = b2[j]; }
  if (j < 16) rk[j] = 0.f;
  if (j < 544) flags[j] = 0u;   // 512 arrive-flags + go + pad; re-zero per replay
}

// cp += c @ W[0:NC]  (fp32, once). grid (16, 8, 2), block 256.
__global__ __launch_bounds__(TPB) void k_cpart(const float* __restrict__ W1,
                                               const float* __restrict__ W2,
                                               const float* __restrict__ c,
                                               float* __restrict__ cp1,
                                               float* __restrict__ cp2) {
  const float* __restrict__ W = blockIdx.z ? W2 : W1;
  float* __restrict__ cp = blockIdx.z ? cp2 : cp1;
  __shared__ float xs[128];
  __shared__ float red[8][256];
  const int tid = threadIdx.x;
  const int cb = blockIdx.x, rc = blockIdx.y;
  const int r0 = rc * 128;
  if (tid < 128) xs[tid] = c[r0 + tid];
  __syncthreads();
  const int cg = tid & 31, rg = tid >> 5;
  const float* __restrict__ wbase = W + (size_t)r0 * N + cb * 256 + cg * 8;
  float a[8] = {0,0,0,0,0,0,0,0};
#pragma unroll
  for (int k = 0; k < 16; ++k) {
    const int r = rg + (k << 3);
    const float xv = xs[r];
    const float4 wa = *reinterpret_cast<const float4*>(wbase + (size_t)r * N);
    const float4 wb = *reinterpret_cast<const float4*>(wbase + (size_t)r * N + 4);
    a[0] = fmaf(wa.x, xv, a[0]); a[1] = fmaf(wa.y, xv, a[1]);
    a[2] = fmaf(wa.z, xv, a[2]); a[3] = fmaf(wa.w, xv, a[3]);
    a[4] = fmaf(wb.x, xv, a[4]); a[5] = fmaf(wb.y, xv, a[5]);
    a[6] = fmaf(wb.z, xv, a[6]); a[7] = fmaf(wb.w, xv, a[7]);
  }
#pragma unroll
  for (int e = 0; e < 8; ++e) red[rg][cg * 8 + e] = a[e];
  __syncthreads();
  float ssum = 0.f;
#pragma unroll
  for (int g = 0; g < 8; ++g) ssum += red[g][tid];
  atomicAdd(&cp[cb * 256 + tid], ssum);
}

// ---------------------------------------------------------------------------
// Grid barrier, monotonic rounds, ALL-RELAXED (no inv/wbl2 anywhere).
// Correctness: every cross-block datum travels sc1 (L3-direct), so there is
// no stale-L2 copy to invalidate; __syncthreads' vmcnt(0) drain orders the
// data stores before the arrival flag store; compiler barriers stop hoisting.
__device__ __forceinline__ void gsync(unsigned* flags, unsigned* go,
                                      const unsigned round,
                                      const int bid, const int tid) {
  __syncthreads();   // drains vmcnt(0): this block's sc1 stores are L3-acked
  if (bid == 0) {
    if (tid == 0) STC(&flags[0], round);
    while (LDC(&flags[tid]) < round || LDC(&flags[tid + 256]) < round) {
      __builtin_amdgcn_s_sleep(1);
    }
    asm volatile("" ::: "memory");
    __syncthreads();
    if (tid == 0) STC(go, round);
  } else {
    if (tid == 0) {
      STC(&flags[bid], round);
      while (LDC(go) < round) {
        __builtin_amdgcn_s_sleep(1);
      }
      asm volatile("" ::: "memory");
    }
    __syncthreads();
  }
}

// ---------------------------------------------------------------------------
// Epilogue of previous phase + build x chunk (everything except the matvec).
// Cross-block buffers (pin, u1, fb*, ycur) use LDC/STC (sc1). ksum is
// block-(0,rc)-private across phases -> normal ld/st.
// Modes: 0=FIRST(x=sig(h)), 1=P2(u1), 2=P3(f,tangent-L1 in), 3=P4(du1,RK),
//        4=PD(df,rk,next-stage x1).
// ---------------------------------------------------------------------------
__device__ __forceinline__ void build_x(
    const int mode,
    const float* __restrict__ pin, const float* __restrict__ cpart,
    float* __restrict__ u1, float* __restrict__ fcur,
    const float* __restrict__ fprev,
    float* __restrict__ ycur, float* __restrict__ ksum,
    float* __restrict__ rk, const int rkIdx, const int s,
    const float csv, const float dtv,
    float (&xs)[128], float (&red)[8][256],
    const int tid, const int cb, const int rc, const int j0) {
  // partial reduce split across all 256 threads (red[0..1][0..127] reused)
  if (mode != 0) {
    const int jl = tid & 127, half = tid >> 7;
    const float* __restrict__ pp = pin + ((half << 4) << 12) + j0 + jl;
    float tv[16];
#pragma unroll
    for (int r = 0; r < 16; ++r) tv[r] = LDC(pp + ((size_t)r << 12));
    float ps = 0.f;
#pragma unroll
    for (int r = 0; r < 16; ++r) ps += tv[r];
    red[half][jl] = ps;
  }
  __syncthreads();

  if (tid < 128) {
    const int j = j0 + tid;
    float xv;
    if (mode == 0) {                       // FIRST: x1 = sig(h)
      xv = sigf(LDC(&ycur[j]));
    } else {
      const float ssum = red[0][tid] + red[1][tid];
      if (mode == 1) {                     // P2: u1 = red + cpart1; x2 = sig(u1)
        const float u = ssum + cpart[j];
        if (cb == 0) STC(&u1[j], u);
        xv = sigf(u);
      } else if (mode == 2) {              // P3: f = red + cpart2; v1 = s0'(ys)*f
        const float fv = ssum + cpart[j];
        if (cb == 0) STC(&fcur[j], fv);
        float ys = LDC(&ycur[j]);
        if (csv != 0.f) ys = fmaf(csv * dtv, LDC(&fprev[j]), ys);
        const float s0 = sigf(ys);
        xv = s0 * (1.f - s0) * fv;
      } else if (mode == 3) {              // P4: du1 = red; v2 = s1'(u1)*du1; RK
        if (cb == 0) {
          const float fc = LDC(&fcur[j]);
          if (s == 0)      ksum[j] = fc;
          else if (s < 3)  ksum[j] = fmaf(2.f, fc, ksum[j]);
          else             STC(&ycur[j],
                               fmaf(dtv * (1.f / 6.f), ksum[j] + fc, LDC(&ycur[j])));
        }
        const float s1 = sigf(LDC(&u1[j]));
        xv = s1 * (1.f - s1) * ssum;
      } else {                             // PD: df = red; rk += df^2; x1 next
        float v = ssum * ssum;
#pragma unroll
        for (int off = 32; off >= 1; off >>= 1) v += __shfl_down(v, off);
        if (cb == 0 && (tid & 63) == 0) atomicAdd(&rk[rkIdx], v);
        float ys = LDC(&ycur[j]);
        if (csv != 0.f) ys = fmaf(csv * dtv, LDC(&fprev[j]), ys);
        xv = sigf(ys);
      }
    }
    xs[tid] = xv;
  }
  __syncthreads();
}

// ---------------------------------------------------------------------------
// AGPR weight storage: 4 dwords per 16-row step, 16 steps per matrix.
#define DECL4(P) unsigned P##_0, P##_1, P##_2, P##_3;

#define LDW(M, K, SRCP)                                                        \
  {                                                                            \
    const size_t off = (size_t)(K << 3) * N;                                   \
    const uint4 q = __builtin_bit_cast(                                        \
        uint4, cvt8(*reinterpret_cast<const float4*>((SRCP) + off),            \
                    *reinterpret_cast<const float4*>((SRCP) + off + 4)));      \
    AW(M##_##K##_0, q.x); AW(M##_##K##_1, q.y);                                \
    AW(M##_##K##_2, q.z); AW(M##_##K##_3, q.w);                                \
  }

#define MV_STEP(M, K)                                                          \
  {                                                                            \
    const float xv = xs[rg + (K << 3)];                                        \
    unsigned d0, d1, d2, d3;                                                   \
    AR(d0, M##_##K##_0); AR(d1, M##_##K##_1);                                  \
    AR(d2, M##_##K##_2); AR(d3, M##_##K##_3);                                  \
    acc[0] = fmaf(lof(d0), xv, acc[0]); acc[1] = fmaf(hif(d0), xv, acc[1]);    \
    acc[2] = fmaf(lof(d1), xv, acc[2]); acc[3] = fmaf(hif(d1), xv, acc[3]);    \
    acc[4] = fmaf(lof(d2), xv, acc[4]); acc[5] = fmaf(hif(d2), xv, acc[5]);    \
    acc[6] = fmaf(lof(d3), xv, acc[6]); acc[7] = fmaf(hif(d3), xv, acc[7]);    \
  }

#define MV16(M)                                                                \
  MV_STEP(M, 0)  MV_STEP(M, 1)  MV_STEP(M, 2)  MV_STEP(M, 3)                  \
  MV_STEP(M, 4)  MV_STEP(M, 5)  MV_STEP(M, 6)  MV_STEP(M, 7)                  \
  MV_STEP(M, 8)  MV_STEP(M, 9)  MV_STEP(M, 10) MV_STEP(M, 11)                 \
  MV_STEP(M, 12) MV_STEP(M, 13) MV_STEP(M, 14) MV_STEP(M, 15)

// One full phase: build x -> matvec from AGPR weights -> block-level column
// reduce -> write partials (sc1). TM = t-row AGPR prefix, COEF = t-row coef.
#define RUN_PHASE(MODE, M, TM, PIN, POUT, CPART, COEF, RKI)                    \
  {                                                                            \
    build_x((MODE), (PIN), (CPART), u1, fcur, fprev, ycur, ksum, rk, (RKI),    \
            s, csv, dtv, xs, red, tid, cb, rc, j0);                            \
    float acc[8] = {0.f, 0.f, 0.f, 0.f, 0.f, 0.f, 0.f, 0.f};                   \
    MV16(M)                                                                    \
    if (doT) {                                                                 \
      unsigned d0, d1, d2, d3;                                                 \
      AR(d0, TM##_0); AR(d1, TM##_1); AR(d2, TM##_2); AR(d3, TM##_3);          \
      const float cf = (COEF);                                                 \
      acc[0] = fmaf(lof(d0), cf, acc[0]); acc[1] = fmaf(hif(d0), cf, acc[1]);  \
      acc[2] = fmaf(lof(d1), cf, acc[2]); acc[3] = fmaf(hif(d1), cf, acc[3]);  \
      acc[4] = fmaf(lof(d2), cf, acc[4]); acc[5] = fmaf(hif(d2), cf, acc[5]);  \
      acc[6] = fmaf(lof(d3), cf, acc[6]); acc[7] = fmaf(hif(d3), cf, acc[7]);  \
    }                                                                          \
    _Pragma("unroll")                                                          \
    for (int e = 0; e < 8; ++e) red[rg][cg * 8 + e] = acc[e];                  \
    __syncthreads();                                                           \
    float ssum = 0.f;                                                          \
    _Pragma("unroll")                                                          \
    for (int g = 0; g < 8; ++g) ssum += red[g][tid];                           \
    STC(&(POUT)[(rc << 12) + cb * 256 + tid], ssum);                           \
  }

// ---------------------------------------------------------------------------
__global__ __launch_bounds__(TPB)
__attribute__((amdgpu_waves_per_eu(2, 2)))
void k_ode(
    const float* __restrict__ W1f, const float* __restrict__ W2f,
    const float* __restrict__ tptr,
    float* __restrict__ partA, float* __restrict__ partB,
    const float* __restrict__ cp1, const float* __restrict__ cp2,
    float* __restrict__ u1, float* __restrict__ fb0, float* __restrict__ fb1,
    float* __restrict__ ycur, float* __restrict__ ksum,
    float* __restrict__ rk, unsigned* flags) {
  __shared__ float xs[128];
  __shared__ float red[8][256];
  const int tid = threadIdx.x;
  const int bid = blockIdx.x;
  const int cb = bid & 15, rc = bid >> 4;
  const int j0 = rc * 128;
  const int cg = tid & 31, rg = tid >> 5;
  unsigned* go = flags + 512;

  // ---- one-time: fp32 -> bf16 (RNE) weight tiles into AGPRs ----
  const size_t colOff = (size_t)(cb * 256 + cg * 8);
  const float* __restrict__ w1p = W1f + (size_t)(NC + j0 + rg) * N + colOff;
  const float* __restrict__ w2p = W2f + (size_t)(NC + j0 + rg) * N + colOff;

  DECL4(g1_0)  DECL4(g1_1)  DECL4(g1_2)  DECL4(g1_3)
  DECL4(g1_4)  DECL4(g1_5)  DECL4(g1_6)  DECL4(g1_7)
  DECL4(g1_8)  DECL4(g1_9)  DECL4(g1_10) DECL4(g1_11)
  DECL4(g1_12) DECL4(g1_13) DECL4(g1_14) DECL4(g1_15)
  DECL4(g2_0)  DECL4(g2_1)  DECL4(g2_2)  DECL4(g2_3)
  DECL4(g2_4)  DECL4(g2_5)  DECL4(g2_6)  DECL4(g2_7)
  DECL4(g2_8)  DECL4(g2_9)  DECL4(g2_10) DECL4(g2_11)
  DECL4(g2_12) DECL4(g2_13) DECL4(g2_14) DECL4(g2_15)
  DECL4(t1) DECL4(t2)

  LDW(g1, 0, w1p)  LDW(g1, 1, w1p)  LDW(g1, 2, w1p)  LDW(g1, 3, w1p)
  LDW(g1, 4, w1p)  LDW(g1, 5, w1p)  LDW(g1, 6, w1p)  LDW(g1, 7, w1p)
  LDW(g1, 8, w1p)  LDW(g1, 9, w1p)  LDW(g1, 10, w1p) LDW(g1, 11, w1p)
  LDW(g1, 12, w1p) LDW(g1, 13, w1p) LDW(g1, 14, w1p) LDW(g1, 15, w1p)
  LDW(g2, 0, w2p)  LDW(g2, 1, w2p)  LDW(g2, 2, w2p)  LDW(g2, 3, w2p)
  LDW(g2, 4, w2p)  LDW(g2, 5, w2p)  LDW(g2, 6, w2p)  LDW(g2, 7, w2p)
  LDW(g2, 8, w2p)  LDW(g2, 9, w2p)  LDW(g2, 10, w2p) LDW(g2, 11, w2p)
  LDW(g2, 12, w2p) LDW(g2, 13, w2p) LDW(g2, 14, w2p) LDW(g2, 15, w2p)

  // t-row (row NC+N) — loaded by every thread (uniform, cheap), used by doT.
  {
    const float* tp1 = W1f + (size_t)(NC + N) * N + colOff;
    const float* tp2 = W2f + (size_t)(NC + N) * N + colOff;
    const uint4 q1 = __builtin_bit_cast(
        uint4, cvt8(*reinterpret_cast<const float4*>(tp1),
                    *reinterpret_cast<const float4*>(tp1 + 4)));
    AW(t1_0, q1.x); AW(t1_1, q1.y); AW(t1_2, q1.z); AW(t1_3, q1.w);
    const uint4 q2 = __builtin_bit_cast(
        uint4, cvt8(*reinterpret_cast<const float4*>(tp2),
                    *reinterpret_cast<const float4*>(tp2 + 4)));
    AW(t2_0, q2.x); AW(t2_1, q2.y); AW(t2_2, q2.z); AW(t2_3, q2.w);
  }
  const bool doT = (rc == 31 && rg == 0);
  const float dtv = tptr[0] * (1.0f / STEPS);

  // ---- 16 evals x 4 phases, grid sync between phases ----
  float* pA = partA;
  float* pB = partB;
  unsigned sn = 0;

  for (int i = 0; i < 16; ++i) {
    const int s = i & 3;
    const float csv = (s == 0) ? 0.f : ((s == 3) ? 1.f : 0.5f);
    const float tcoef = ((float)(i >> 2) + csv) * dtv;
    float* fcur = (i & 1) ? fb1 : fb0;
    const float* fprev = (i & 1) ? fb0 : fb1;

    // P1: u1 partials = x1 @ W1_state (FIRST for i=0, PD otherwise)
    RUN_PHASE((i == 0) ? 0 : 4, g1, t1, pB, pA, cp1, tcoef, i - 1)
    { float* tp = pA; pA = pB; pB = tp; }
    ++sn; gsync(flags, go, sn, bid, tid);

    // P2: f partials = sig(u1+cp1) @ W2_state
    RUN_PHASE(1, g2, t2, pB, pA, cp1, tcoef, 0)
    { float* tp = pA; pA = pB; pB = tp; }
    ++sn; gsync(flags, go, sn, bid, tid);

    // P3: du1 partials = (sig'(ys)*f) @ W1_state, t-coef 1
    RUN_PHASE(2, g1, t1, pB, pA, cp2, 1.f, 0)
    { float* tp = pA; pA = pB; pB = tp; }
    ++sn; gsync(flags, go, sn, bid, tid);

    // P4: df partials = (sig'(u1)*du1) @ W2_state, t-coef 1; RK bookkeeping
    RUN_PHASE(3, g2, t2, pB, pA, cp2, 1.f, 0)
    { float* tp = pA; pA = pB; pB = tp; }
    if (i < 15) { ++sn; gsync(flags, go, sn, bid, tid); }
  }
}

// Reduce the final P4 partials -> rk[15]; copy ycur -> out.
// (Kernel boundary after k_ode provides system-scope visibility.)
__global__ __launch_bounds__(128) void k_last(const float* __restrict__ part_in,
                                              const float* __restrict__ ycur,
                                              float* __restrict__ rk,
                                              float* __restrict__ out) {
  const int tid = threadIdx.x;
  const int j = blockIdx.x * 128 + tid;
  float df = 0.f;
#pragma unroll 8
  for (int r = 0; r < 32; ++r) df += part_in[(r << 12) + j];
  float v = df * df;
#pragma unroll
  for (int off = 32; off >= 1; off >>= 1) v += __shfl_down(v, off);
  if ((tid & 63) == 0) atomicAdd(&rk[15], v);
  out[j] = ycur[j];
}

__global__ void k_out(const float* __restrict__ rk, const float* __restrict__ tptr,
                      float* __restrict__ out) {
  if (threadIdx.x == 0) {
    const float dtv = tptr[0] * (1.0f / STEPS);
    float r = 0.f;
    for (int st = 0; st < STEPS; ++st)
      r += rk[4 * st] + 2.f * rk[4 * st + 1] + 2.f * rk[4 * st + 2] + rk[4 * st + 3];
    out[N] = r * (dtv / 6.f) * (1.0f / N);
  }
}

// ---------------------------------------------------------------------------
extern "C" void kernel_launch(void* const* d_in, const int* in_sizes, int n_in,
                              void* d_out, int out_size, void* d_ws, size_t ws_size,
                              hipStream_t stream) {
  const float* h  = (const float*)d_in[0];
  const float* t  = (const float*)d_in[1];
  const float* c  = (const float*)d_in[2];
  const float* W1 = (const float*)d_in[3];
  const float* b1 = (const float*)d_in[4];
  const float* W2 = (const float*)d_in[5];
  const float* b2 = (const float*)d_in[6];
  float* out = (float*)d_out;

  // ws: fp32 buffers + flags (~1.2 MB) — weights live in AGPRs.
  float* fp    = (float*)d_ws;
  float* partA = fp;                     // 32*4096
  float* partB = partA + 32 * N;
  float* cp1   = partB + 32 * N;
  float* cp2   = cp1 + N;
  float* u1    = cp2 + N;
  float* fb0   = u1 + N;
  float* fb1   = fb0 + N;
  float* ycur  = fb1 + N;
  float* ksum  = ycur + N;
  float* rk    = ksum + N;               // 16
  unsigned* flags = (unsigned*)(rk + 16); // 512 flags + go + pad

  k_init<<<16, TPB, 0, stream>>>(h, b1, b2, ycur, cp1, cp2, rk, flags);
  k_cpart<<<dim3(16, 8, 2), TPB, 0, stream>>>(W1, W2, c, cp1, cp2);

  k_ode<<<NBLK, TPB, 0, stream>>>(W1, W2, t, partA, partB, cp1, cp2,
                                  u1, fb0, fb1, ycur, ksum, rk, flags);

  k_last<<<32, 128, 0, stream>>>(partB, ycur, rk, out);
  k_out<<<1, 64, 0, stream>>>(rk, t, out);
}

// Round 10
// 1019.247 us; speedup vs baseline: 4.1477x; 1.0205x over previous
//
#include <hip/hip_runtime.h>

// STATE=4096, CDIM=1024, fan_in=5121. RK4 x 4 steps = 16 aug-dynamics evals
// = 64 matvec phases. Persistent kernel, weights pinned in AGPRs (r7).
// Sync evolution: r7 acquire-spin (buffer_inv/iter, 58us) -> r8 single
// acquire (wbl2+inv x ~1000/barrier, 26us) -> r9 all-relaxed sc1 (L3-direct,
// 13us) -> r10: the residual was the SINGLE-ADDRESS 'go' hotspot (511 waves
// polling one L3 sector; bank-serialized). Fix: distributed go array — 512
// slots, 16B-padded; block0's 256 threads broadcast in parallel; each waiter
// spins on its OWN slot. Zero contention, one L3 observation per waiter.
#define N      4096
#define NC     1024
#define STEPS  4
#define TPB    256
#define NBLK   512

typedef unsigned short us8 __attribute__((ext_vector_type(8)));

// Agent-scope relaxed = sc1 (L2-bypass, L3-coherent), no cache ops.
#define LDC(p)    __hip_atomic_load((p), __ATOMIC_RELAXED, __HIP_MEMORY_SCOPE_AGENT)
#define STC(p, v) __hip_atomic_store((p), (v), __ATOMIC_RELAXED, __HIP_MEMORY_SCOPE_AGENT)

__device__ __forceinline__ float bf2f(unsigned short u) {
  union { unsigned int i; float f; } v; v.i = ((unsigned int)u) << 16; return v.f;
}
__device__ __forceinline__ unsigned short f2bf(float f) {
  union { float f; unsigned int i; } v; v.f = f;
  const unsigned int u = v.i;
  return (unsigned short)((u + 0x7FFFu + ((u >> 16) & 1u)) >> 16);  // RNE
}
__device__ __forceinline__ float sigf(float x) { return 1.0f / (1.0f + __expf(-x)); }
__device__ __forceinline__ us8 cvt8(const float4 a, const float4 b) {
  us8 o;
  o[0] = f2bf(a.x); o[1] = f2bf(a.y); o[2] = f2bf(a.z); o[3] = f2bf(a.w);
  o[4] = f2bf(b.x); o[5] = f2bf(b.y); o[6] = f2bf(b.z); o[7] = f2bf(b.w);
  return o;
}
// bf16 pair extraction from a packed dword — bit-identical to bf2f of each u16
__device__ __forceinline__ float lof(unsigned d) {
  union { unsigned u; float f; } v; v.u = d << 16; return v.f;
}
__device__ __forceinline__ float hif(unsigned d) {
  union { unsigned u; float f; } v; v.u = d & 0xffff0000u; return v.f;
}

// AGPR pin/read. Volatile: not sinkable/hoistable/CSE-able/remat-able.
#define AW(dst, src) \
  asm volatile("v_accvgpr_write_b32 %0, %1" : "=a"(dst) : "v"(src))
#define AR(dst, src) \
  asm volatile("v_accvgpr_read_b32 %0, %1" : "=v"(dst) : "a"(src))

// ---------------------------------------------------------------------------
// flags[0..511] = arrive flags; flags[512 + 4*b] = go slot for block b
// (16B padding: 4 slots per 64B sector). Total 512 + 2048 = 2560 dwords.
__global__ __launch_bounds__(TPB) void k_init(const float* __restrict__ h,
                                              const float* __restrict__ b1,
                                              const float* __restrict__ b2,
                                              float* __restrict__ ycur,
                                              float* __restrict__ cp1,
                                              float* __restrict__ cp2,
                                              float* __restrict__ rk,
                                              unsigned* __restrict__ flags) {
  const int j = blockIdx.x * TPB + threadIdx.x;
  if (j < N) { ycur[j] = h[j]; cp1[j] = b1[j]; cp2[j] = b2[j]; }
  if (j < 16) rk[j] = 0.f;
  if (j < 2560) flags[j] = 0u;   // re-zero every graph replay
}

// cp += c @ W[0:NC]  (fp32, once). grid (16, 8, 2), block 256.
__global__ __launch_bounds__(TPB) void k_cpart(const float* __restrict__ W1,
                                               const float* __restrict__ W2,
                                               const float* __restrict__ c,
                                               float* __restrict__ cp1,
                                               float* __restrict__ cp2) {
  const float* __restrict__ W = blockIdx.z ? W2 : W1;
  float* __restrict__ cp = blockIdx.z ? cp2 : cp1;
  __shared__ float xs[128];
  __shared__ float red[8][256];
  const int tid = threadIdx.x;
  const int cb = blockIdx.x, rc = blockIdx.y;
  const int r0 = rc * 128;
  if (tid < 128) xs[tid] = c[r0 + tid];
  __syncthreads();
  const int cg = tid & 31, rg = tid >> 5;
  const float* __restrict__ wbase = W + (size_t)r0 * N + cb * 256 + cg * 8;
  float a[8] = {0,0,0,0,0,0,0,0};
#pragma unroll
  for (int k = 0; k < 16; ++k) {
    const int r = rg + (k << 3);
    const float xv = xs[r];
    const float4 wa = *reinterpret_cast<const float4*>(wbase + (size_t)r * N);
    const float4 wb = *reinterpret_cast<const float4*>(wbase + (size_t)r * N + 4);
    a[0] = fmaf(wa.x, xv, a[0]); a[1] = fmaf(wa.y, xv, a[1]);
    a[2] = fmaf(wa.z, xv, a[2]); a[3] = fmaf(wa.w, xv, a[3]);
    a[4] = fmaf(wb.x, xv, a[4]); a[5] = fmaf(wb.y, xv, a[5]);
    a[6] = fmaf(wb.z, xv, a[6]); a[7] = fmaf(wb.w, xv, a[7]);
  }
#pragma unroll
  for (int e = 0; e < 8; ++e) red[rg][cg * 8 + e] = a[e];
  __syncthreads();
  float ssum = 0.f;
#pragma unroll
  for (int g = 0; g < 8; ++g) ssum += red[g][tid];
  atomicAdd(&cp[cb * 256 + tid], ssum);
}

// ---------------------------------------------------------------------------
// Grid barrier, monotonic rounds, all-relaxed sc1, DISTRIBUTED go broadcast.
// Arrive: block b release-free sc1 store flag[b]=round (data already L3-acked
// by __syncthreads' vmcnt(0) drain). Block0: 256 threads poll the 512 flags
// (distinct addresses), syncthreads, then broadcast round into 512 padded go
// slots in parallel. Waiter b spins on ITS OWN slot -> no L3 hotspot.
__device__ __forceinline__ void gsync(unsigned* flags, const unsigned round,
                                      const int bid, const int tid) {
  unsigned* goArr = flags + 512;
  __syncthreads();   // drains vmcnt(0): this block's sc1 stores are L3-acked
  if (bid == 0) {
    if (tid == 0) STC(&flags[0], round);
    while (LDC(&flags[tid]) < round || LDC(&flags[tid + 256]) < round) {
      __builtin_amdgcn_s_sleep(1);
    }
    asm volatile("" ::: "memory");
    __syncthreads();                     // all 512 flags observed
    STC(&goArr[tid * 4], round);
    STC(&goArr[(tid + 256) * 4], round);
  } else {
    if (tid == 0) {
      STC(&flags[bid], round);
      while (LDC(&goArr[bid * 4]) < round) {
        __builtin_amdgcn_s_sleep(1);
      }
      asm volatile("" ::: "memory");
    }
    __syncthreads();
  }
}

// ---------------------------------------------------------------------------
// Epilogue of previous phase + build x chunk (everything except the matvec).
// Cross-block buffers (pin, u1, fb*, ycur) use LDC/STC (sc1). ksum is
// block-(0,rc)-private across phases -> normal ld/st.
// Modes: 0=FIRST(x=sig(h)), 1=P2(u1), 2=P3(f,tangent-L1 in), 3=P4(du1,RK),
//        4=PD(df,rk,next-stage x1).
// ---------------------------------------------------------------------------
__device__ __forceinline__ void build_x(
    const int mode,
    const float* __restrict__ pin, const float* __restrict__ cpart,
    float* __restrict__ u1, float* __restrict__ fcur,
    const float* __restrict__ fprev,
    float* __restrict__ ycur, float* __restrict__ ksum,
    float* __restrict__ rk, const int rkIdx, const int s,
    const float csv, const float dtv,
    float (&xs)[128], float (&red)[8][256],
    const int tid, const int cb, const int rc, const int j0) {
  // partial reduce split across all 256 threads (red[0..1][0..127] reused)
  if (mode != 0) {
    const int jl = tid & 127, half = tid >> 7;
    const float* __restrict__ pp = pin + ((half << 4) << 12) + j0 + jl;
    float tv[16];
#pragma unroll
    for (int r = 0; r < 16; ++r) tv[r] = LDC(pp + ((size_t)r << 12));
    float ps = 0.f;
#pragma unroll
    for (int r = 0; r < 16; ++r) ps += tv[r];
    red[half][jl] = ps;
  }
  __syncthreads();

  if (tid < 128) {
    const int j = j0 + tid;
    float xv;
    if (mode == 0) {                       // FIRST: x1 = sig(h)
      xv = sigf(LDC(&ycur[j]));
    } else {
      const float ssum = red[0][tid] + red[1][tid];
      if (mode == 1) {                     // P2: u1 = red + cpart1; x2 = sig(u1)
        const float u = ssum + cpart[j];
        if (cb == 0) STC(&u1[j], u);
        xv = sigf(u);
      } else if (mode == 2) {              // P3: f = red + cpart2; v1 = s0'(ys)*f
        const float fv = ssum + cpart[j];
        if (cb == 0) STC(&fcur[j], fv);
        float ys = LDC(&ycur[j]);
        if (csv != 0.f) ys = fmaf(csv * dtv, LDC(&fprev[j]), ys);
        const float s0 = sigf(ys);
        xv = s0 * (1.f - s0) * fv;
      } else if (mode == 3) {              // P4: du1 = red; v2 = s1'(u1)*du1; RK
        if (cb == 0) {
          const float fc = LDC(&fcur[j]);
          if (s == 0)      ksum[j] = fc;
          else if (s < 3)  ksum[j] = fmaf(2.f, fc, ksum[j]);
          else             STC(&ycur[j],
                               fmaf(dtv * (1.f / 6.f), ksum[j] + fc, LDC(&ycur[j])));
        }
        const float s1 = sigf(LDC(&u1[j]));
        xv = s1 * (1.f - s1) * ssum;
      } else {                             // PD: df = red; rk += df^2; x1 next
        float v = ssum * ssum;
#pragma unroll
        for (int off = 32; off >= 1; off >>= 1) v += __shfl_down(v, off);
        if (cb == 0 && (tid & 63) == 0) atomicAdd(&rk[rkIdx], v);
        float ys = LDC(&ycur[j]);
        if (csv != 0.f) ys = fmaf(csv * dtv, LDC(&fprev[j]), ys);
        xv = sigf(ys);
      }
    }
    xs[tid] = xv;
  }
  __syncthreads();
}

// ---------------------------------------------------------------------------
// AGPR weight storage: 4 dwords per 16-row step, 16 steps per matrix.
#define DECL4(P) unsigned P##_0, P##_1, P##_2, P##_3;

#define LDW(M, K, SRCP)                                                        \
  {                                                                            \
    const size_t off = (size_t)(K << 3) * N;                                   \
    const uint4 q = __builtin_bit_cast(                                        \
        uint4, cvt8(*reinterpret_cast<const float4*>((SRCP) + off),            \
                    *reinterpret_cast<const float4*>((SRCP) + off + 4)));      \
    AW(M##_##K##_0, q.x); AW(M##_##K##_1, q.y);                                \
    AW(M##_##K##_2, q.z); AW(M##_##K##_3, q.w);                                \
  }

#define MV_STEP(M, K)                                                          \
  {                                                                            \
    const float xv = xs[rg + (K << 3)];                                        \
    unsigned d0, d1, d2, d3;                                                   \
    AR(d0, M##_##K##_0); AR(d1, M##_##K##_1);                                  \
    AR(d2, M##_##K##_2); AR(d3, M##_##K##_3);                                  \
    acc[0] = fmaf(lof(d0), xv, acc[0]); acc[1] = fmaf(hif(d0), xv, acc[1]);    \
    acc[2] = fmaf(lof(d1), xv, acc[2]); acc[3] = fmaf(hif(d1), xv, acc[3]);    \
    acc[4] = fmaf(lof(d2), xv, acc[4]); acc[5] = fmaf(hif(d2), xv, acc[5]);    \
    acc[6] = fmaf(lof(d3), xv, acc[6]); acc[7] = fmaf(hif(d3), xv, acc[7]);    \
  }

#define MV16(M)                                                                \
  MV_STEP(M, 0)  MV_STEP(M, 1)  MV_STEP(M, 2)  MV_STEP(M, 3)                  \
  MV_STEP(M, 4)  MV_STEP(M, 5)  MV_STEP(M, 6)  MV_STEP(M, 7)                  \
  MV_STEP(M, 8)  MV_STEP(M, 9)  MV_STEP(M, 10) MV_STEP(M, 11)                 \
  MV_STEP(M, 12) MV_STEP(M, 13) MV_STEP(M, 14) MV_STEP(M, 15)

// One full phase: build x -> matvec from AGPR weights -> block-level column
// reduce -> write partials (sc1). TM = t-row AGPR prefix, COEF = t-row coef.
#define RUN_PHASE(MODE, M, TM, PIN, POUT, CPART, COEF, RKI)                    \
  {                                                                            \
    build_x((MODE), (PIN), (CPART), u1, fcur, fprev, ycur, ksum, rk, (RKI),    \
            s, csv, dtv, xs, red, tid, cb, rc, j0);                            \
    float acc[8] = {0.f, 0.f, 0.f, 0.f, 0.f, 0.f, 0.f, 0.f};                   \
    MV16(M)                                                                    \
    if (doT) {                                                                 \
      unsigned d0, d1, d2, d3;                                                 \
      AR(d0, TM##_0); AR(d1, TM##_1); AR(d2, TM##_2); AR(d3, TM##_3);          \
      const float cf = (COEF);                                                 \
      acc[0] = fmaf(lof(d0), cf, acc[0]); acc[1] = fmaf(hif(d0), cf, acc[1]);  \
      acc[2] = fmaf(lof(d1), cf, acc[2]); acc[3] = fmaf(hif(d1), cf, acc[3]);  \
      acc[4] = fmaf(lof(d2), cf, acc[4]); acc[5] = fmaf(hif(d2), cf, acc[5]);  \
      acc[6] = fmaf(lof(d3), cf, acc[6]); acc[7] = fmaf(hif(d3), cf, acc[7]);  \
    }                                                                          \
    _Pragma("unroll")                                                          \
    for (int e = 0; e < 8; ++e) red[rg][cg * 8 + e] = acc[e];                  \
    __syncthreads();                                                           \
    float ssum = 0.f;                                                          \
    _Pragma("unroll")                                                          \
    for (int g = 0; g < 8; ++g) ssum += red[g][tid];                           \
    STC(&(POUT)[(rc << 12) + cb * 256 + tid], ssum);                           \
  }

// ---------------------------------------------------------------------------
__global__ __launch_bounds__(TPB)
__attribute__((amdgpu_waves_per_eu(2, 2)))
void k_ode(
    const float* __restrict__ W1f, const float* __restrict__ W2f,
    const float* __restrict__ tptr,
    float* __restrict__ partA, float* __restrict__ partB,
    const float* __restrict__ cp1, const float* __restrict__ cp2,
    float* __restrict__ u1, float* __restrict__ fb0, float* __restrict__ fb1,
    float* __restrict__ ycur, float* __restrict__ ksum,
    float* __restrict__ rk, unsigned* flags) {
  __shared__ float xs[128];
  __shared__ float red[8][256];
  const int tid = threadIdx.x;
  const int bid = blockIdx.x;
  const int cb = bid & 15, rc = bid >> 4;
  const int j0 = rc * 128;
  const int cg = tid & 31, rg = tid >> 5;

  // ---- one-time: fp32 -> bf16 (RNE) weight tiles into AGPRs ----
  const size_t colOff = (size_t)(cb * 256 + cg * 8);
  const float* __restrict__ w1p = W1f + (size_t)(NC + j0 + rg) * N + colOff;
  const float* __restrict__ w2p = W2f + (size_t)(NC + j0 + rg) * N + colOff;

  DECL4(g1_0)  DECL4(g1_1)  DECL4(g1_2)  DECL4(g1_3)
  DECL4(g1_4)  DECL4(g1_5)  DECL4(g1_6)  DECL4(g1_7)
  DECL4(g1_8)  DECL4(g1_9)  DECL4(g1_10) DECL4(g1_11)
  DECL4(g1_12) DECL4(g1_13) DECL4(g1_14) DECL4(g1_15)
  DECL4(g2_0)  DECL4(g2_1)  DECL4(g2_2)  DECL4(g2_3)
  DECL4(g2_4)  DECL4(g2_5)  DECL4(g2_6)  DECL4(g2_7)
  DECL4(g2_8)  DECL4(g2_9)  DECL4(g2_10) DECL4(g2_11)
  DECL4(g2_12) DECL4(g2_13) DECL4(g2_14) DECL4(g2_15)
  DECL4(t1) DECL4(t2)

  LDW(g1, 0, w1p)  LDW(g1, 1, w1p)  LDW(g1, 2, w1p)  LDW(g1, 3, w1p)
  LDW(g1, 4, w1p)  LDW(g1, 5, w1p)  LDW(g1, 6, w1p)  LDW(g1, 7, w1p)
  LDW(g1, 8, w1p)  LDW(g1, 9, w1p)  LDW(g1, 10, w1p) LDW(g1, 11, w1p)
  LDW(g1, 12, w1p) LDW(g1, 13, w1p) LDW(g1, 14, w1p) LDW(g1, 15, w1p)
  LDW(g2, 0, w2p)  LDW(g2, 1, w2p)  LDW(g2, 2, w2p)  LDW(g2, 3, w2p)
  LDW(g2, 4, w2p)  LDW(g2, 5, w2p)  LDW(g2, 6, w2p)  LDW(g2, 7, w2p)
  LDW(g2, 8, w2p)  LDW(g2, 9, w2p)  LDW(g2, 10, w2p) LDW(g2, 11, w2p)
  LDW(g2, 12, w2p) LDW(g2, 13, w2p) LDW(g2, 14, w2p) LDW(g2, 15, w2p)

  // t-row (row NC+N) — loaded by every thread (uniform, cheap), used by doT.
  {
    const float* tp1 = W1f + (size_t)(NC + N) * N + colOff;
    const float* tp2 = W2f + (size_t)(NC + N) * N + colOff;
    const uint4 q1 = __builtin_bit_cast(
        uint4, cvt8(*reinterpret_cast<const float4*>(tp1),
                    *reinterpret_cast<const float4*>(tp1 + 4)));
    AW(t1_0, q1.x); AW(t1_1, q1.y); AW(t1_2, q1.z); AW(t1_3, q1.w);
    const uint4 q2 = __builtin_bit_cast(
        uint4, cvt8(*reinterpret_cast<const float4*>(tp2),
                    *reinterpret_cast<const float4*>(tp2 + 4)));
    AW(t2_0, q2.x); AW(t2_1, q2.y); AW(t2_2, q2.z); AW(t2_3, q2.w);
  }
  const bool doT = (rc == 31 && rg == 0);
  const float dtv = tptr[0] * (1.0f / STEPS);

  // ---- 16 evals x 4 phases, grid sync between phases ----
  float* pA = partA;
  float* pB = partB;
  unsigned sn = 0;

  for (int i = 0; i < 16; ++i) {
    const int s = i & 3;
    const float csv = (s == 0) ? 0.f : ((s == 3) ? 1.f : 0.5f);
    const float tcoef = ((float)(i >> 2) + csv) * dtv;
    float* fcur = (i & 1) ? fb1 : fb0;
    const float* fprev = (i & 1) ? fb0 : fb1;

    // P1: u1 partials = x1 @ W1_state (FIRST for i=0, PD otherwise)
    RUN_PHASE((i == 0) ? 0 : 4, g1, t1, pB, pA, cp1, tcoef, i - 1)
    { float* tp = pA; pA = pB; pB = tp; }
    ++sn; gsync(flags, sn, bid, tid);

    // P2: f partials = sig(u1+cp1) @ W2_state
    RUN_PHASE(1, g2, t2, pB, pA, cp1, tcoef, 0)
    { float* tp = pA; pA = pB; pB = tp; }
    ++sn; gsync(flags, sn, bid, tid);

    // P3: du1 partials = (sig'(ys)*f) @ W1_state, t-coef 1
    RUN_PHASE(2, g1, t1, pB, pA, cp2, 1.f, 0)
    { float* tp = pA; pA = pB; pB = tp; }
    ++sn; gsync(flags, sn, bid, tid);

    // P4: df partials = (sig'(u1)*du1) @ W2_state, t-coef 1; RK bookkeeping
    RUN_PHASE(3, g2, t2, pB, pA, cp2, 1.f, 0)
    { float* tp = pA; pA = pB; pB = tp; }
    if (i < 15) { ++sn; gsync(flags, sn, bid, tid); }
  }
}

// Reduce the final P4 partials -> rk[15]; copy ycur -> out.
// (Kernel boundary after k_ode provides system-scope visibility.)
__global__ __launch_bounds__(128) void k_last(const float* __restrict__ part_in,
                                              const float* __restrict__ ycur,
                                              float* __restrict__ rk,
                                              float* __restrict__ out) {
  const int tid = threadIdx.x;
  const int j = blockIdx.x * 128 + tid;
  float df = 0.f;
#pragma unroll 8
  for (int r = 0; r < 32; ++r) df += part_in[(r << 12) + j];
  float v = df * df;
#pragma unroll
  for (int off = 32; off >= 1; off >>= 1) v += __shfl_down(v, off);
  if ((tid & 63) == 0) atomicAdd(&rk[15], v);
  out[j] = ycur[j];
}

__global__ void k_out(const float* __restrict__ rk, const float* __restrict__ tptr,
                      float* __restrict__ out) {
  if (threadIdx.x == 0) {
    const float dtv = tptr[0] * (1.0f / STEPS);
    float r = 0.f;
    for (int st = 0; st < STEPS; ++st)
      r += rk[4 * st] + 2.f * rk[4 * st + 1] + 2.f * rk[4 * st + 2] + rk[4 * st + 3];
    out[N] = r * (dtv / 6.f) * (1.0f / N);
  }
}

// ---------------------------------------------------------------------------
extern "C" void kernel_launch(void* const* d_in, const int* in_sizes, int n_in,
                              void* d_out, int out_size, void* d_ws, size_t ws_size,
                              hipStream_t stream) {
  const float* h  = (const float*)d_in[0];
  const float* t  = (const float*)d_in[1];
  const float* c  = (const float*)d_in[2];
  const float* W1 = (const float*)d_in[3];
  const float* b1 = (const float*)d_in[4];
  const float* W2 = (const float*)d_in[5];
  const float* b2 = (const float*)d_in[6];
  float* out = (float*)d_out;

  // ws: fp32 buffers + flags (~1.3 MB) — weights live in AGPRs.
  float* fp    = (float*)d_ws;
  float* partA = fp;                     // 32*4096
  float* partB = partA + 32 * N;
  float* cp1   = partB + 32 * N;
  float* cp2   = cp1 + N;
  float* u1    = cp2 + N;
  float* fb0   = u1 + N;
  float* fb1   = fb0 + N;
  float* ycur  = fb1 + N;
  float* ksum  = ycur + N;
  float* rk    = ksum + N;               // 16
  unsigned* flags = (unsigned*)(rk + 16); // 512 arrive + 512*4 padded go slots

  k_init<<<16, TPB, 0, stream>>>(h, b1, b2, ycur, cp1, cp2, rk, flags);
  k_cpart<<<dim3(16, 8, 2), TPB, 0, stream>>>(W1, W2, c, cp1, cp2);

  k_ode<<<NBLK, TPB, 0, stream>>>(W1, W2, t, partA, partB, cp1, cp2,
                                  u1, fb0, fb1, ycur, ksum, rk, flags);

  k_last<<<32, 128, 0, stream>>>(partB, ycur, rk, out);
  k_out<<<1, 64, 0, stream>>>(rk, t, out);
}